// Round 1
// baseline (12819.788 us; speedup 1.0000x reference)
//
#include <hip/hip_runtime.h>
#include <cmath>
#include <cstddef>
#include <cstdint>

// Problem constants (B=1)
#define DIMM   1024
#define HEADS  16
#define HEADD  64
#define FFN_H  4096
#define LE     8
#define TOPK   2
#define DIM_E  512
#define DIM_S  1024
#define NTOK   2048   // B*S

// ---------------------------------------------------------------------------
// RMSNorm: one block (256 threads) per row of 1024
// ---------------------------------------------------------------------------
__global__ __launch_bounds__(256) void rmsnorm_kernel(
    const float* __restrict__ x, const float* __restrict__ g,
    float* __restrict__ y)
{
    const int row = blockIdx.x;
    const int t = threadIdx.x;
    const float* xr = x + (size_t)row * DIMM;
    float4 v = *(const float4*)(xr + t * 4);
    float ss = v.x * v.x + v.y * v.y + v.z * v.z + v.w * v.w;
    #pragma unroll
    for (int off = 32; off > 0; off >>= 1) ss += __shfl_down(ss, off, 64);
    __shared__ float ws[4];
    if ((t & 63) == 0) ws[t >> 6] = ss;
    __syncthreads();
    const float tot = ws[0] + ws[1] + ws[2] + ws[3];
    const float scale = rsqrtf(tot * (1.0f / DIMM) + 1e-6f);
    const float4 gv = *(const float4*)(g + t * 4);
    float4 o;
    o.x = v.x * scale * gv.x; o.y = v.y * scale * gv.y;
    o.z = v.z * scale * gv.z; o.w = v.w * scale * gv.w;
    *(float4*)(y + (size_t)row * DIMM + t * 4) = o;
}

// ---------------------------------------------------------------------------
// fp32 GEMM: C[M,N] = A[M,K] @ W[K,N] (+ add). 128x128 tile, KT=16, 8x8/thread.
// M,N multiples of 128; K multiple of 16.
// ---------------------------------------------------------------------------
__global__ __launch_bounds__(256) void gemm_f32(
    const float* __restrict__ A, const float* __restrict__ W,
    const float* __restrict__ add, float* __restrict__ C,
    int M, int N, int K)
{
    __shared__ float As[16][132];   // [kk][m], padded
    __shared__ float Wt[16][128];   // [kk][n]
    const int t = threadIdx.x;
    const int m0 = blockIdx.y * 128, n0 = blockIdx.x * 128;
    const int tx = t & 15, ty = t >> 4;
    const int arow = t >> 2, aq = (t & 3) * 4;
    const int wk = t >> 5, wn = (t & 31) * 4;
    float acc[8][8];
    #pragma unroll
    for (int u = 0; u < 8; ++u)
        #pragma unroll
        for (int v = 0; v < 8; ++v) acc[u][v] = 0.f;

    for (int k0 = 0; k0 < K; k0 += 16) {
        const float4 a0 = *(const float4*)&A[(size_t)(m0 + arow) * K + k0 + aq];
        const float4 a1 = *(const float4*)&A[(size_t)(m0 + arow + 64) * K + k0 + aq];
        const float4 w0 = *(const float4*)&W[(size_t)(k0 + wk) * N + n0 + wn];
        const float4 w1 = *(const float4*)&W[(size_t)(k0 + wk + 8) * N + n0 + wn];
        As[aq + 0][arow] = a0.x; As[aq + 1][arow] = a0.y;
        As[aq + 2][arow] = a0.z; As[aq + 3][arow] = a0.w;
        As[aq + 0][arow + 64] = a1.x; As[aq + 1][arow + 64] = a1.y;
        As[aq + 2][arow + 64] = a1.z; As[aq + 3][arow + 64] = a1.w;
        *(float4*)&Wt[wk][wn] = w0;
        *(float4*)&Wt[wk + 8][wn] = w1;
        __syncthreads();
        #pragma unroll
        for (int kk = 0; kk < 16; ++kk) {
            float a[8], w[8];
            #pragma unroll
            for (int u = 0; u < 8; ++u) a[u] = As[kk][ty * 8 + u];
            #pragma unroll
            for (int v = 0; v < 8; ++v) w[v] = Wt[kk][tx * 8 + v];
            #pragma unroll
            for (int u = 0; u < 8; ++u)
                #pragma unroll
                for (int v = 0; v < 8; ++v) acc[u][v] += a[u] * w[v];
        }
        __syncthreads();
    }
    #pragma unroll
    for (int u = 0; u < 8; ++u) {
        const size_t base = (size_t)(m0 + ty * 8 + u) * N + n0 + tx * 8;
        float4 r0 = make_float4(acc[u][0], acc[u][1], acc[u][2], acc[u][3]);
        float4 r1 = make_float4(acc[u][4], acc[u][5], acc[u][6], acc[u][7]);
        if (add) {
            const float4 b0 = *(const float4*)(add + base);
            const float4 b1 = *(const float4*)(add + base + 4);
            r0.x += b0.x; r0.y += b0.y; r0.z += b0.z; r0.w += b0.w;
            r1.x += b1.x; r1.y += b1.y; r1.z += b1.z; r1.w += b1.w;
        }
        *(float4*)(C + base) = r0;
        *(float4*)(C + base + 4) = r1;
    }
}

// ---------------------------------------------------------------------------
// Rotary in-place on q and k sections of qkv [NTOK][3072]
// ---------------------------------------------------------------------------
__global__ __launch_bounds__(256) void rotary_kernel(float* __restrict__ qkv)
{
    const int i = blockIdx.x * 256 + threadIdx.x;   // NTOK*16*32 threads
    const int s = i >> 9;
    const int rem = i & 511;
    const int h = rem >> 5;
    const int j = rem & 31;
    // inv_freq = 10000^(-j/32) = exp(-j * ln(10000)/32)
    const float inv_freq = __expf(-(float)j * (9.210340371976184f / 32.f));
    const float f = (float)s * inv_freq;
    float sn, cs;
    sincosf(f, &sn, &cs);
    float* base = qkv + (size_t)s * 3072 + h * 64 + j;
    const float q1 = base[0], q2 = base[32];
    base[0]  = q1 * cs + q2 * sn;
    base[32] = -q1 * sn + q2 * cs;
    const float k1 = base[1024], k2 = base[1024 + 32];
    base[1024]      = k1 * cs + k2 * sn;
    base[1024 + 32] = -k1 * sn + k2 * cs;
}

// ---------------------------------------------------------------------------
// Flash-style attention, causal + same-document mask.
// Grid: (HEADS, NTOK/128). 128 threads; 1 thread = 1 query row.
// ---------------------------------------------------------------------------
__global__ __launch_bounds__(128) void attn_kernel(
    const float* __restrict__ qkv, const int* __restrict__ doc,
    float* __restrict__ out)
{
    const int h = blockIdx.x;
    const int rb = blockIdx.y;
    const int t = threadIdx.x;
    const int r = rb * 128 + t;
    __shared__ float Ks[64][64];
    __shared__ float Vs[64][64];
    __shared__ int docs[64];
    float q[64], o[64];
    const float* qrow = qkv + (size_t)r * 3072 + h * 64;
    #pragma unroll
    for (int d4 = 0; d4 < 16; ++d4) {
        const float4 v = *(const float4*)(qrow + d4 * 4);
        q[d4 * 4 + 0] = v.x * 0.125f; q[d4 * 4 + 1] = v.y * 0.125f;
        q[d4 * 4 + 2] = v.z * 0.125f; q[d4 * 4 + 3] = v.w * 0.125f;
    }
    #pragma unroll
    for (int d = 0; d < 64; ++d) o[d] = 0.f;
    float m = -INFINITY, l = 0.f;
    const int myDoc = doc[r];
    const int ntiles = rb * 2 + 2;
    const int krow = t >> 1;
    const int khalf = (t & 1) * 32;
    for (int kt = 0; kt < ntiles; ++kt) {
        const float* kr = qkv + (size_t)(kt * 64 + krow) * 3072 + 1024 + h * 64 + khalf;
        #pragma unroll
        for (int u = 0; u < 8; ++u) {
            *(float4*)&Ks[krow][khalf + u * 4] = *(const float4*)(kr + u * 4);
            *(float4*)&Vs[krow][khalf + u * 4] = *(const float4*)(kr + 1024 + u * 4);
        }
        if (t < 64) docs[t] = doc[kt * 64 + t];
        __syncthreads();
        const int kbase = kt * 64;
        #pragma unroll 1
        for (int c = 0; c < 8; ++c) {
            float sv[8];
            float cmax = -INFINITY;
            #pragma unroll
            for (int i = 0; i < 8; ++i) {
                const int kk = c * 8 + i;
                float accd = 0.f;
                #pragma unroll
                for (int d = 0; d < 64; ++d) accd += q[d] * Ks[kk][d];
                const bool valid = (kbase + kk <= r) && (docs[kk] == myDoc);
                sv[i] = valid ? accd : -INFINITY;
                cmax = fmaxf(cmax, sv[i]);
            }
            if (cmax == -INFINITY) continue;   // whole chunk masked
            const float mnew = fmaxf(m, cmax);
            const float alpha = __expf(m - mnew);   // 0 if m was -inf
            float p[8], psum = 0.f;
            #pragma unroll
            for (int i = 0; i < 8; ++i) {
                p[i] = (sv[i] == -INFINITY) ? 0.f : __expf(sv[i] - mnew);
                psum += p[i];
            }
            l = l * alpha + psum;
            m = mnew;
            #pragma unroll
            for (int d = 0; d < 64; ++d) {
                float tmp = o[d] * alpha;
                #pragma unroll
                for (int i = 0; i < 8; ++i) tmp += p[i] * Vs[c * 8 + i][d];
                o[d] = tmp;
            }
        }
        __syncthreads();
    }
    const float inv = 1.f / l;
    float* orow = out + (size_t)r * DIMM + h * 64;
    #pragma unroll
    for (int d4 = 0; d4 < 16; ++d4) {
        float4 v;
        v.x = o[d4 * 4 + 0] * inv; v.y = o[d4 * 4 + 1] * inv;
        v.z = o[d4 * 4 + 2] * inv; v.w = o[d4 * 4 + 3] * inv;
        *(float4*)(orow + d4 * 4) = v;
    }
}

// ---------------------------------------------------------------------------
// SwiGLU: g[n][j] = silu(h[n][j]) * h[n][j+H], H = 1<<shift
// ---------------------------------------------------------------------------
__global__ __launch_bounds__(256) void swiglu_kernel(
    const float* __restrict__ h, float* __restrict__ g, int shift)
{
    const int i = blockIdx.x * 256 + threadIdx.x;
    const int H = 1 << shift;
    const int n = i >> shift;
    const int j = i & (H - 1);
    const float* hr = h + ((size_t)n << (shift + 1));
    const float a = hr[j], b = hr[H + j];
    g[i] = (a / (1.f + __expf(-a))) * b;
}

// ---------------------------------------------------------------------------
// Elementwise add (float4): o = a + b, grid covers NTOK*DIMM/4 lanes
// ---------------------------------------------------------------------------
__global__ __launch_bounds__(256) void add_kernel(
    const float* __restrict__ a, const float* __restrict__ b,
    float* __restrict__ o)
{
    const int i = blockIdx.x * 256 + threadIdx.x;
    float4 av = *(const float4*)(a + (size_t)i * 4);
    const float4 bv = *(const float4*)(b + (size_t)i * 4);
    av.x += bv.x; av.y += bv.y; av.z += bv.z; av.w += bv.w;
    *(float4*)(o + (size_t)i * 4) = av;
}

// ---------------------------------------------------------------------------
// MoE router: one block (64 threads) per token. Computes normalized top-2 scores.
// ---------------------------------------------------------------------------
__global__ __launch_bounds__(64) void router_kernel(
    const float* __restrict__ xf, const float* __restrict__ tkeys,
    const float* __restrict__ rbias, const int* __restrict__ idx,
    const float* __restrict__ vals, float* __restrict__ sc)
{
    const int n = blockIdx.x;
    const int t = threadIdx.x;
    const int e0 = idx[n * 2 + 0], e1 = idx[n * 2 + 1];
    float a0 = 0.f, a1 = 0.f;
    for (int d = t; d < DIMM; d += 64) {
        const float xv = xf[(size_t)n * DIMM + d];
        a0 += xv * tkeys[d * LE + e0];
        a1 += xv * tkeys[d * LE + e1];
    }
    #pragma unroll
    for (int off = 32; off > 0; off >>= 1) {
        a0 += __shfl_down(a0, off, 64);
        a1 += __shfl_down(a1, off, 64);
    }
    if (t == 0) {
        const float v0 = vals[n * 2 + 0] + a0 + rbias[e0];
        const float v1 = vals[n * 2 + 1] + a1 + rbias[e1];
        const float s0 = 1.f / (1.f + __expf(-v0));
        const float s1 = 1.f / (1.f + __expf(-v1));
        const float inv = 1.f / (s0 + s1);   // RSF = 1.0
        sc[n * 2 + 0] = s0 * inv;
        sc[n * 2 + 1] = s1 * inv;
    }
}

// ---------------------------------------------------------------------------
// MoE experts: one block (256 threads) per token; loops its 2 slots.
// experts layout: [3][LE][DIMM][DIM_E] for this layer.
// ---------------------------------------------------------------------------
__global__ __launch_bounds__(256) void expert_kernel(
    const float* __restrict__ xf, const float* __restrict__ experts,
    const int* __restrict__ idx, const float* __restrict__ sc,
    float* __restrict__ y)
{
    const int n = blockIdx.x;
    const int t = threadIdx.x;
    __shared__ float xs[DIMM];
    __shared__ float p[DIM_E];
    *(float4*)&xs[t * 4] = *(const float4*)&xf[(size_t)n * DIMM + t * 4];
    __syncthreads();
    float yacc[4] = {0.f, 0.f, 0.f, 0.f};
    for (int slot = 0; slot < TOPK; ++slot) {
        const int e = idx[n * 2 + slot];
        const float scale = sc[n * 2 + slot];
        const float* W0 = experts + (size_t)e * (DIMM * DIM_E);
        const float* W1 = experts + (size_t)(LE + e) * (DIMM * DIM_E);
        const float* W2 = experts + (size_t)(2 * LE + e) * (DIMM * DIM_E);
        float h1a = 0.f, h1b = 0.f, h2a = 0.f, h2b = 0.f;
        #pragma unroll 4
        for (int d = 0; d < DIMM; ++d) {
            const float xd = xs[d];
            h1a += xd * W0[d * DIM_E + t];
            h1b += xd * W0[d * DIM_E + t + 256];
            h2a += xd * W1[d * DIM_E + t];
            h2b += xd * W1[d * DIM_E + t + 256];
        }
        p[t]       = (h1a / (1.f + __expf(-h1a))) * h2a;
        p[t + 256] = (h1b / (1.f + __expf(-h1b))) * h2b;
        __syncthreads();
        #pragma unroll
        for (int u = 0; u < 4; ++u) {
            const float* w2r = W2 + (size_t)(t + u * 256) * DIM_E;
            float acc = 0.f;
            #pragma unroll 8
            for (int hh = 0; hh < DIM_E; ++hh) acc += p[hh] * w2r[hh];
            yacc[u] += scale * acc;
        }
        __syncthreads();   // protect p before next slot overwrites
    }
    #pragma unroll
    for (int u = 0; u < 4; ++u)
        y[(size_t)n * DIMM + t + u * 256] = yacc[u];
}

// ---------------------------------------------------------------------------
// Host-side orchestration
// ---------------------------------------------------------------------------
struct Scratch {
    float *xn, *qkv, *attnO, *xi, *xf, *hup, *yex, *sc, *xA, *xB;
    float *gact;   // alias of qkv..attnO region (8M floats)
};

static void attn_block(const float* x_in, const float* aw, const float* ao,
                       const float* ag, const int* doc, Scratch& w,
                       hipStream_t s)
{
    rmsnorm_kernel<<<NTOK, 256, 0, s>>>(x_in, ag, w.xn);
    gemm_f32<<<dim3(3 * DIMM / 128, NTOK / 128), 256, 0, s>>>(
        w.xn, aw, nullptr, w.qkv, NTOK, 3 * DIMM, DIMM);
    rotary_kernel<<<(NTOK * 512) / 256, 256, 0, s>>>(w.qkv);
    attn_kernel<<<dim3(HEADS, NTOK / 128), 128, 0, s>>>(w.qkv, doc, w.attnO);
    gemm_f32<<<dim3(DIMM / 128, NTOK / 128), 256, 0, s>>>(
        w.attnO, ao, x_in, w.xi, NTOK, DIMM, DIMM);
}

static void dense_layer_run(const float* x_in, float* x_out,
                            const float* aw, const float* ao,
                            const float* up, const float* down,
                            const float* ag, const float* fg,
                            const int* doc, Scratch& w, hipStream_t s)
{
    attn_block(x_in, aw, ao, ag, doc, w, s);
    rmsnorm_kernel<<<NTOK, 256, 0, s>>>(w.xi, fg, w.xf);
    gemm_f32<<<dim3(2 * FFN_H / 128, NTOK / 128), 256, 0, s>>>(
        w.xf, up, nullptr, w.hup, NTOK, 2 * FFN_H, DIMM);
    swiglu_kernel<<<(NTOK * FFN_H) / 256, 256, 0, s>>>(w.hup, w.gact, 12);
    gemm_f32<<<dim3(DIMM / 128, NTOK / 128), 256, 0, s>>>(
        w.gact, down, w.xi, x_out, NTOK, DIMM, FFN_H);
}

static void moe_layer_run(const float* x_in, float* x_out,
                          const float* aw, const float* ao,
                          const float* ag, const float* fg,
                          const float* experts, const float* tkeys,
                          const float* rbias, const float* sup,
                          const float* sdn, const int* idx, const float* vals,
                          const int* doc, Scratch& w, hipStream_t s)
{
    attn_block(x_in, aw, ao, ag, doc, w, s);
    rmsnorm_kernel<<<NTOK, 256, 0, s>>>(w.xi, fg, w.xf);
    router_kernel<<<NTOK, 64, 0, s>>>(w.xf, tkeys, rbias, idx, vals, w.sc);
    expert_kernel<<<NTOK, 256, 0, s>>>(w.xf, experts, idx, w.sc, w.yex);
    gemm_f32<<<dim3(2 * DIM_S / 128, NTOK / 128), 256, 0, s>>>(
        w.xf, sup, nullptr, w.hup, NTOK, 2 * DIM_S, DIMM);
    swiglu_kernel<<<(NTOK * DIM_S) / 256, 256, 0, s>>>(w.hup, w.gact, 10);
    // xn is dead here; reuse as tmp = shared_out + expert_y
    gemm_f32<<<dim3(DIMM / 128, NTOK / 128), 256, 0, s>>>(
        w.gact, sdn, w.yex, w.xn, NTOK, DIMM, DIM_S);
    add_kernel<<<(NTOK * DIMM / 4) / 256, 256, 0, s>>>(w.xn, w.xi, x_out);
}

extern "C" void kernel_launch(void* const* d_in, const int* in_sizes, int n_in,
                              void* d_out, int out_size, void* d_ws, size_t ws_size,
                              hipStream_t stream)
{
    (void)in_sizes; (void)n_in; (void)out_size; (void)ws_size;
    const float* x       = (const float*)d_in[0];
    const int*   doc     = (const int*)d_in[1];
    const int*   indices = (const int*)d_in[2];
    const float* values  = (const float*)d_in[3];
    const float* d_aw    = (const float*)d_in[4];
    const float* d_ao    = (const float*)d_in[5];
    const float* d_up    = (const float*)d_in[6];
    const float* d_down  = (const float*)d_in[7];
    const float* d_ag    = (const float*)d_in[8];
    const float* d_fg    = (const float*)d_in[9];
    const float* m_aw    = (const float*)d_in[10];
    const float* m_ao    = (const float*)d_in[11];
    const float* m_ag    = (const float*)d_in[12];
    const float* m_fg    = (const float*)d_in[13];
    const float* m_ex    = (const float*)d_in[14];
    const float* m_tk    = (const float*)d_in[15];
    const float* m_rb    = (const float*)d_in[16];
    const float* m_sup   = (const float*)d_in[17];
    const float* m_sdn   = (const float*)d_in[18];

    float* p = (float*)d_ws;
    Scratch w;
    w.xn    = p; p += (size_t)NTOK * DIMM;       // 2M
    w.qkv   = p; p += (size_t)NTOK * 3 * DIMM;   // 6M
    w.attnO = p; p += (size_t)NTOK * DIMM;       // 2M (contiguous after qkv!)
    w.xi    = p; p += (size_t)NTOK * DIMM;
    w.xf    = p; p += (size_t)NTOK * DIMM;
    w.hup   = p; p += (size_t)NTOK * 2 * FFN_H;  // 16M
    w.yex   = p; p += (size_t)NTOK * DIMM;
    w.sc    = p; p += (size_t)NTOK * TOPK;
    w.xA    = p; p += (size_t)NTOK * DIMM;
    w.xB    = p; p += (size_t)NTOK * DIMM;
    w.gact  = w.qkv;   // SwiGLU output overlays dead qkv+attnO (8M floats)

    float* out = (float*)d_out;

    // layer 0: dense
    dense_layer_run(x, w.xA, d_aw, d_ao, d_up, d_down, d_ag, d_fg, doc, w, stream);
    // layers 1,2: MoE
    const size_t EXL = (size_t)3 * LE * DIMM * DIM_E;
    moe_layer_run(w.xA, w.xB,
                  m_aw, m_ao, m_ag, m_fg,
                  m_ex, m_tk, m_rb, m_sup, m_sdn,
                  indices, values, doc, w, stream);
    moe_layer_run(w.xB, w.xA,
                  m_aw + (size_t)DIMM * 3 * DIMM, m_ao + (size_t)DIMM * DIMM,
                  m_ag + DIMM, m_fg + DIMM,
                  m_ex + EXL, m_tk + DIMM * LE, m_rb + LE,
                  m_sup + (size_t)DIMM * 2 * DIM_S, m_sdn + (size_t)DIM_S * DIMM,
                  indices + (size_t)NTOK * TOPK, values + (size_t)NTOK * TOPK,
                  doc, w, stream);
    // layer 3: dense
    dense_layer_run(w.xA, out,
                    d_aw + (size_t)DIMM * 3 * DIMM, d_ao + (size_t)DIMM * DIMM,
                    d_up + (size_t)DIMM * 2 * FFN_H, d_down + (size_t)FFN_H * DIMM,
                    d_ag + DIMM, d_fg + DIMM, doc, w, stream);
}

// Round 2
// 4853.791 us; speedup vs baseline: 2.6412x; 2.6412x over previous
//
#include <hip/hip_runtime.h>
#include <cmath>
#include <cstddef>
#include <cstdint>

#define DIMM   1024
#define HEADS  16
#define HEADD  64
#define FFN_H  4096
#define LE     8
#define TOPK   2
#define DIM_E  512
#define DIM_S  1024
#define NTOK   2048

typedef __bf16 bf16x8 __attribute__((ext_vector_type(8)));
typedef float  f32x4  __attribute__((ext_vector_type(4)));

union BF4 { __bf16 h[4]; uint2 u; };

// ---------------------------------------------------------------------------
// RMSNorm -> bf16 output. One block (256 thr) per row of 1024.
// ---------------------------------------------------------------------------
__global__ __launch_bounds__(256) void rmsnorm_bf(
    const float* __restrict__ x, const float* __restrict__ g,
    __bf16* __restrict__ y)
{
    const int row = blockIdx.x;
    const int t = threadIdx.x;
    const float* xr = x + (size_t)row * DIMM;
    float4 v = *(const float4*)(xr + t * 4);
    float ss = v.x * v.x + v.y * v.y + v.z * v.z + v.w * v.w;
    #pragma unroll
    for (int off = 32; off > 0; off >>= 1) ss += __shfl_down(ss, off, 64);
    __shared__ float ws[4];
    if ((t & 63) == 0) ws[t >> 6] = ss;
    __syncthreads();
    const float tot = ws[0] + ws[1] + ws[2] + ws[3];
    const float scale = rsqrtf(tot * (1.0f / DIMM) + 1e-6f);
    const float4 gv = *(const float4*)(g + t * 4);
    BF4 o;
    o.h[0] = (__bf16)(v.x * scale * gv.x);
    o.h[1] = (__bf16)(v.y * scale * gv.y);
    o.h[2] = (__bf16)(v.z * scale * gv.z);
    o.h[3] = (__bf16)(v.w * scale * gv.w);
    *(uint2*)(y + (size_t)row * DIMM + t * 4) = o.u;
}

// ---------------------------------------------------------------------------
// bf16 MFMA GEMM: C[M,N] = A[M,K] @ BT[N,K]^T (+ add). fp32 out.
// 128x128 tile, BK=32, 4 waves in 2x2, each wave 4x4 of 16x16x32 MFMAs.
// ---------------------------------------------------------------------------
__global__ __launch_bounds__(256) void gemm_bf(
    const __bf16* __restrict__ A, const __bf16* __restrict__ BT,
    const float* __restrict__ add, float* __restrict__ C,
    int M, int N, int K)
{
    __shared__ __bf16 As[128 * 32];
    __shared__ __bf16 Bs[128 * 32];
    const int t = threadIdx.x;
    const int m0 = blockIdx.y * 128, n0 = blockIdx.x * 128;
    const int lane = t & 63;
    const int wv = t >> 6;
    const int mw = (wv >> 1) * 64, nw = (wv & 1) * 64;
    const int fr = lane & 15;           // fragment row (m or n)
    const int fk = (lane >> 4) * 8;     // fragment k offset
    const int r0 = t >> 2;              // staging row (0..63)
    const int q0 = (t & 3) * 8;         // staging k offset

    f32x4 acc[4][4];
    #pragma unroll
    for (int i = 0; i < 4; ++i)
        #pragma unroll
        for (int j = 0; j < 4; ++j) acc[i][j] = (f32x4){0.f, 0.f, 0.f, 0.f};

    for (int k0 = 0; k0 < K; k0 += 32) {
        const bf16x8 a0 = *(const bf16x8*)(A + (size_t)(m0 + r0) * K + k0 + q0);
        const bf16x8 a1 = *(const bf16x8*)(A + (size_t)(m0 + 64 + r0) * K + k0 + q0);
        const bf16x8 b0 = *(const bf16x8*)(BT + (size_t)(n0 + r0) * K + k0 + q0);
        const bf16x8 b1 = *(const bf16x8*)(BT + (size_t)(n0 + 64 + r0) * K + k0 + q0);
        __syncthreads();
        *(bf16x8*)&As[r0 * 32 + q0] = a0;
        *(bf16x8*)&As[(64 + r0) * 32 + q0] = a1;
        *(bf16x8*)&Bs[r0 * 32 + q0] = b0;
        *(bf16x8*)&Bs[(64 + r0) * 32 + q0] = b1;
        __syncthreads();
        bf16x8 af[4], bfr[4];
        #pragma unroll
        for (int i = 0; i < 4; ++i) {
            af[i]  = *(const bf16x8*)&As[(mw + i * 16 + fr) * 32 + fk];
            bfr[i] = *(const bf16x8*)&Bs[(nw + i * 16 + fr) * 32 + fk];
        }
        #pragma unroll
        for (int i = 0; i < 4; ++i)
            #pragma unroll
            for (int j = 0; j < 4; ++j)
                acc[i][j] = __builtin_amdgcn_mfma_f32_16x16x32_bf16(
                    af[i], bfr[j], acc[i][j], 0, 0, 0);
    }
    const int cn = lane & 15, cr = (lane >> 4) * 4;
    #pragma unroll
    for (int i = 0; i < 4; ++i)
        #pragma unroll
        for (int j = 0; j < 4; ++j)
            #pragma unroll
            for (int r = 0; r < 4; ++r) {
                const size_t off = (size_t)(m0 + mw + i * 16 + cr + r) * N
                                 + (n0 + nw + j * 16 + cn);
                C[off] = acc[i][j][r] + (add ? add[off] : 0.f);
            }
}

// ---------------------------------------------------------------------------
// Transpose + cast fp32[R][C] -> bf16[C][R], batched over blockIdx.z
// ---------------------------------------------------------------------------
__global__ __launch_bounds__(256) void transpose_cast(
    const float* __restrict__ in, __bf16* __restrict__ out, int R, int C)
{
    __shared__ float tile[32][33];
    const int bx = blockIdx.x * 32, by = blockIdx.y * 32;
    const size_t bz = (size_t)blockIdx.z * R * C;
    const int tx = threadIdx.x & 31, ty = threadIdx.x >> 5;
    const float* ip = in + bz;
    __bf16* op = out + bz;
    #pragma unroll
    for (int i = 0; i < 4; ++i)
        tile[ty + i * 8][tx] = ip[(size_t)(by + ty + i * 8) * C + bx + tx];
    __syncthreads();
    #pragma unroll
    for (int i = 0; i < 4; ++i)
        op[(size_t)(bx + ty + i * 8) * R + by + tx] = (__bf16)tile[tx][ty + i * 8];
}

// ---------------------------------------------------------------------------
// W2 [e][d][h] fp32 -> bf16 [d][e*512+h]  (per-layer, 8*1024*512 elems)
// ---------------------------------------------------------------------------
__global__ __launch_bounds__(256) void cast_w2(
    const float* __restrict__ in, __bf16* __restrict__ out)
{
    const int i = blockIdx.x * 256 + threadIdx.x;
    const int d = i >> 12, r = i & 4095;
    const int e = r >> 9, h = r & 511;
    out[i] = (__bf16)in[(size_t)e * (DIMM * DIM_E) + d * DIM_E + h];
}

// ---------------------------------------------------------------------------
// Rotary in-place on q and k sections of qkv [NTOK][3072] (fp32)
// ---------------------------------------------------------------------------
__global__ __launch_bounds__(256) void rotary_kernel(float* __restrict__ qkv)
{
    const int i = blockIdx.x * 256 + threadIdx.x;
    const int s = i >> 9;
    const int rem = i & 511;
    const int h = rem >> 5;
    const int j = rem & 31;
    const float inv_freq = __expf(-(float)j * (9.210340371976184f / 32.f));
    const float f = (float)s * inv_freq;
    float sn, cs;
    sincosf(f, &sn, &cs);
    float* base = qkv + (size_t)s * 3072 + h * 64 + j;
    const float q1 = base[0], q2 = base[32];
    base[0]  = q1 * cs + q2 * sn;
    base[32] = -q1 * sn + q2 * cs;
    const float k1 = base[1024], k2 = base[1024 + 32];
    base[1024]      = k1 * cs + k2 * sn;
    base[1024 + 32] = -k1 * sn + k2 * cs;
}

// ---------------------------------------------------------------------------
// Flash-style attention, causal + same-doc mask. fp32 in, bf16 out.
// ---------------------------------------------------------------------------
__global__ __launch_bounds__(128) void attn_kernel(
    const float* __restrict__ qkv, const int* __restrict__ doc,
    __bf16* __restrict__ out)
{
    const int h = blockIdx.x;
    const int rb = blockIdx.y;
    const int t = threadIdx.x;
    const int r = rb * 128 + t;
    __shared__ float Ks[64][64];
    __shared__ float Vs[64][64];
    __shared__ int docs[64];
    float q[64], o[64];
    const float* qrow = qkv + (size_t)r * 3072 + h * 64;
    #pragma unroll
    for (int d4 = 0; d4 < 16; ++d4) {
        const float4 v = *(const float4*)(qrow + d4 * 4);
        q[d4 * 4 + 0] = v.x * 0.125f; q[d4 * 4 + 1] = v.y * 0.125f;
        q[d4 * 4 + 2] = v.z * 0.125f; q[d4 * 4 + 3] = v.w * 0.125f;
    }
    #pragma unroll
    for (int d = 0; d < 64; ++d) o[d] = 0.f;
    float m = -INFINITY, l = 0.f;
    const int myDoc = doc[r];
    const int ntiles = rb * 2 + 2;
    const int krow = t >> 1;
    const int khalf = (t & 1) * 32;
    for (int kt = 0; kt < ntiles; ++kt) {
        const float* kr = qkv + (size_t)(kt * 64 + krow) * 3072 + 1024 + h * 64 + khalf;
        #pragma unroll
        for (int u = 0; u < 8; ++u) {
            *(float4*)&Ks[krow][khalf + u * 4] = *(const float4*)(kr + u * 4);
            *(float4*)&Vs[krow][khalf + u * 4] = *(const float4*)(kr + 1024 + u * 4);
        }
        if (t < 64) docs[t] = doc[kt * 64 + t];
        __syncthreads();
        const int kbase = kt * 64;
        #pragma unroll 1
        for (int c = 0; c < 8; ++c) {
            float sv[8];
            float cmax = -INFINITY;
            #pragma unroll
            for (int i = 0; i < 8; ++i) {
                const int kk = c * 8 + i;
                float accd = 0.f;
                #pragma unroll
                for (int d = 0; d < 64; ++d) accd += q[d] * Ks[kk][d];
                const bool valid = (kbase + kk <= r) && (docs[kk] == myDoc);
                sv[i] = valid ? accd : -INFINITY;
                cmax = fmaxf(cmax, sv[i]);
            }
            if (cmax == -INFINITY) continue;
            const float mnew = fmaxf(m, cmax);
            const float alpha = __expf(m - mnew);
            float p[8], psum = 0.f;
            #pragma unroll
            for (int i = 0; i < 8; ++i) {
                p[i] = (sv[i] == -INFINITY) ? 0.f : __expf(sv[i] - mnew);
                psum += p[i];
            }
            l = l * alpha + psum;
            m = mnew;
            #pragma unroll
            for (int d = 0; d < 64; ++d) {
                float tmp = o[d] * alpha;
                #pragma unroll
                for (int i = 0; i < 8; ++i) tmp += p[i] * Vs[c * 8 + i][d];
                o[d] = tmp;
            }
        }
        __syncthreads();
    }
    const float inv = 1.f / l;
    __bf16* orow = out + (size_t)r * DIMM + h * 64;
    #pragma unroll
    for (int d4 = 0; d4 < 16; ++d4) {
        BF4 v;
        v.h[0] = (__bf16)(o[d4 * 4 + 0] * inv);
        v.h[1] = (__bf16)(o[d4 * 4 + 1] * inv);
        v.h[2] = (__bf16)(o[d4 * 4 + 2] * inv);
        v.h[3] = (__bf16)(o[d4 * 4 + 3] * inv);
        *(uint2*)(orow + d4 * 4) = v.u;
    }
}

// ---------------------------------------------------------------------------
// SwiGLU: g[n][j] = silu(h[n][j]) * h[n][j+H], H=1<<shift; bf16 out, 4/thread
// ---------------------------------------------------------------------------
__global__ __launch_bounds__(256) void swiglu_bf(
    const float* __restrict__ h, __bf16* __restrict__ g, int shift)
{
    const int i4 = blockIdx.x * 256 + threadIdx.x;
    const int H = 1 << shift;
    const int n = (i4 * 4) >> shift;
    const int j = (i4 * 4) & (H - 1);
    const float* hr = h + ((size_t)n << (shift + 1));
    const float4 a = *(const float4*)(hr + j);
    const float4 b = *(const float4*)(hr + H + j);
    BF4 o;
    o.h[0] = (__bf16)((a.x / (1.f + __expf(-a.x))) * b.x);
    o.h[1] = (__bf16)((a.y / (1.f + __expf(-a.y))) * b.y);
    o.h[2] = (__bf16)((a.z / (1.f + __expf(-a.z))) * b.z);
    o.h[3] = (__bf16)((a.w / (1.f + __expf(-a.w))) * b.w);
    *(uint2*)(g + (size_t)i4 * 4) = o.u;
}

// ---------------------------------------------------------------------------
// p~[n][e*512+h] = silu(h1)*h2 * sc[n][e]   (bf16 out, 4/thread)
// ---------------------------------------------------------------------------
__global__ __launch_bounds__(256) void pmask_bf(
    const float* __restrict__ h1, const float* __restrict__ h2,
    const float* __restrict__ sc, __bf16* __restrict__ p)
{
    const int i4 = blockIdx.x * 256 + threadIdx.x;
    const int n = i4 >> 10;
    const int e = (i4 & 1023) >> 7;   // (kk4)>>9 with kk4=(i4&1023)*4
    const float s = sc[n * LE + e];
    const float4 a = *(const float4*)(h1 + (size_t)i4 * 4);
    const float4 b = *(const float4*)(h2 + (size_t)i4 * 4);
    BF4 o;
    o.h[0] = (__bf16)((a.x / (1.f + __expf(-a.x))) * b.x * s);
    o.h[1] = (__bf16)((a.y / (1.f + __expf(-a.y))) * b.y * s);
    o.h[2] = (__bf16)((a.z / (1.f + __expf(-a.z))) * b.z * s);
    o.h[3] = (__bf16)((a.w / (1.f + __expf(-a.w))) * b.w * s);
    *(uint2*)(p + (size_t)i4 * 4) = o.u;
}

// ---------------------------------------------------------------------------
// Router: sc[n][e] dense (0 for unselected; duplicate idx accumulates)
// ---------------------------------------------------------------------------
__global__ __launch_bounds__(64) void router_bf(
    const __bf16* __restrict__ xf, const float* __restrict__ tkeys,
    const float* __restrict__ rbias, const int* __restrict__ idx,
    const float* __restrict__ vals, float* __restrict__ sc)
{
    const int n = blockIdx.x;
    const int t = threadIdx.x;
    const int e0 = idx[n * 2 + 0], e1 = idx[n * 2 + 1];
    float a0 = 0.f, a1 = 0.f;
    for (int d = t; d < DIMM; d += 64) {
        const float xv = (float)xf[(size_t)n * DIMM + d];
        a0 += xv * tkeys[d * LE + e0];
        a1 += xv * tkeys[d * LE + e1];
    }
    #pragma unroll
    for (int off = 32; off > 0; off >>= 1) {
        a0 += __shfl_down(a0, off, 64);
        a1 += __shfl_down(a1, off, 64);
    }
    if (t == 0) {
        const float v0 = vals[n * 2 + 0] + a0 + rbias[e0];
        const float v1 = vals[n * 2 + 1] + a1 + rbias[e1];
        const float s0 = 1.f / (1.f + __expf(-v0));
        const float s1 = 1.f / (1.f + __expf(-v1));
        const float inv = 1.f / (s0 + s1);
        float r[LE];
        #pragma unroll
        for (int e = 0; e < LE; ++e) r[e] = 0.f;
        r[e0] += s0 * inv;
        r[e1] += s1 * inv;
        #pragma unroll
        for (int e = 0; e < LE; ++e) sc[n * LE + e] = r[e];
    }
}

// ---------------------------------------------------------------------------
// Host orchestration
// ---------------------------------------------------------------------------
struct Scratch {
    float *qkv, *xi, *h12, *t1, *sc, *xA, *xB;
    __bf16 *xn_bf, *attnO_bf, *xf_bf, *wbuf, *gact_bf, *gs_bf;
};

static void attn_block(const float* x_in, const __bf16* awT, const __bf16* aoT,
                       const float* ag, const int* doc, Scratch& w, hipStream_t s)
{
    rmsnorm_bf<<<NTOK, 256, 0, s>>>(x_in, ag, w.xn_bf);
    gemm_bf<<<dim3(24, 16), 256, 0, s>>>(w.xn_bf, awT, nullptr, w.qkv, NTOK, 3072, 1024);
    rotary_kernel<<<(NTOK * 512) / 256, 256, 0, s>>>(w.qkv);
    attn_kernel<<<dim3(HEADS, NTOK / 128), 128, 0, s>>>(w.qkv, doc, w.attnO_bf);
    gemm_bf<<<dim3(8, 16), 256, 0, s>>>(w.attnO_bf, aoT, x_in, w.xi, NTOK, 1024, 1024);
}

static void dense_layer_run(const float* x_in, float* x_out,
                            const float* aw, const float* ao,
                            const float* up, const float* down,
                            const float* ag, const float* fg,
                            const int* doc, Scratch& w, hipStream_t s)
{
    __bf16* awT = w.wbuf;
    __bf16* aoT = w.wbuf + 3145728;
    __bf16* upT = w.wbuf + 4194304;
    __bf16* dnT = w.wbuf + 12582912;
    transpose_cast<<<dim3(96, 32, 1), 256, 0, s>>>(aw, awT, 1024, 3072);
    transpose_cast<<<dim3(32, 32, 1), 256, 0, s>>>(ao, aoT, 1024, 1024);
    transpose_cast<<<dim3(256, 32, 1), 256, 0, s>>>(up, upT, 1024, 8192);
    transpose_cast<<<dim3(32, 128, 1), 256, 0, s>>>(down, dnT, 4096, 1024);
    attn_block(x_in, awT, aoT, ag, doc, w, s);
    rmsnorm_bf<<<NTOK, 256, 0, s>>>(w.xi, fg, w.xf_bf);
    gemm_bf<<<dim3(64, 16), 256, 0, s>>>(w.xf_bf, upT, nullptr, w.h12, NTOK, 8192, 1024);
    swiglu_bf<<<(NTOK * FFN_H / 4) / 256, 256, 0, s>>>(w.h12, w.gact_bf, 12);
    gemm_bf<<<dim3(8, 16), 256, 0, s>>>(w.gact_bf, dnT, w.xi, x_out, NTOK, 1024, 4096);
}

static void moe_layer_run(const float* x_in, float* x_out,
                          const float* aw, const float* ao,
                          const float* ag, const float* fg,
                          const float* experts, const float* tkeys,
                          const float* rbias, const float* sup,
                          const float* sdn, const int* idx, const float* vals,
                          const int* doc, Scratch& w, hipStream_t s)
{
    __bf16* awT  = w.wbuf;
    __bf16* aoT  = w.wbuf + 3145728;
    __bf16* w0T  = w.wbuf + 4194304;
    __bf16* w1T  = w.wbuf + 8388608;
    __bf16* w2c  = w.wbuf + 12582912;
    __bf16* supT = w.wbuf + 16777216;
    __bf16* sdnT = w.wbuf + 18874368;
    const size_t EW = (size_t)LE * DIMM * DIM_E;   // 4194304
    transpose_cast<<<dim3(96, 32, 1), 256, 0, s>>>(aw, awT, 1024, 3072);
    transpose_cast<<<dim3(32, 32, 1), 256, 0, s>>>(ao, aoT, 1024, 1024);
    transpose_cast<<<dim3(16, 32, 8), 256, 0, s>>>(experts, w0T, 1024, 512);
    transpose_cast<<<dim3(16, 32, 8), 256, 0, s>>>(experts + EW, w1T, 1024, 512);
    cast_w2<<<16384, 256, 0, s>>>(experts + 2 * EW, w2c);
    transpose_cast<<<dim3(64, 32, 1), 256, 0, s>>>(sup, supT, 1024, 2048);
    transpose_cast<<<dim3(32, 32, 1), 256, 0, s>>>(sdn, sdnT, 1024, 1024);

    attn_block(x_in, awT, aoT, ag, doc, w, s);
    rmsnorm_bf<<<NTOK, 256, 0, s>>>(w.xi, fg, w.xf_bf);
    router_bf<<<NTOK, 64, 0, s>>>(w.xf_bf, tkeys, rbias, idx, vals, w.sc);
    float* h1 = w.h12;
    float* h2 = w.h12 + 8388608;
    gemm_bf<<<dim3(32, 16), 256, 0, s>>>(w.xf_bf, w0T, nullptr, h1, NTOK, 4096, 1024);
    gemm_bf<<<dim3(32, 16), 256, 0, s>>>(w.xf_bf, w1T, nullptr, h2, NTOK, 4096, 1024);
    pmask_bf<<<(NTOK * 4096 / 4) / 256, 256, 0, s>>>(h1, h2, w.sc, w.gact_bf);
    // shared expert (reuses h12 after pmask consumed h1/h2)
    gemm_bf<<<dim3(16, 16), 256, 0, s>>>(w.xf_bf, supT, nullptr, w.h12, NTOK, 2048, 1024);
    swiglu_bf<<<(NTOK * DIM_S / 4) / 256, 256, 0, s>>>(w.h12, w.gs_bf, 10);
    gemm_bf<<<dim3(8, 16), 256, 0, s>>>(w.gs_bf, sdnT, w.xi, w.t1, NTOK, 1024, 1024);
    // expert combine GEMM, add shared+residual path
    gemm_bf<<<dim3(8, 16), 256, 0, s>>>(w.gact_bf, w2c, w.t1, x_out, NTOK, 1024, 4096);
}

extern "C" void kernel_launch(void* const* d_in, const int* in_sizes, int n_in,
                              void* d_out, int out_size, void* d_ws, size_t ws_size,
                              hipStream_t stream)
{
    (void)in_sizes; (void)n_in; (void)out_size; (void)ws_size;
    const float* x       = (const float*)d_in[0];
    const int*   doc     = (const int*)d_in[1];
    const int*   indices = (const int*)d_in[2];
    const float* values  = (const float*)d_in[3];
    const float* d_aw    = (const float*)d_in[4];
    const float* d_ao    = (const float*)d_in[5];
    const float* d_up    = (const float*)d_in[6];
    const float* d_down  = (const float*)d_in[7];
    const float* d_ag    = (const float*)d_in[8];
    const float* d_fg    = (const float*)d_in[9];
    const float* m_aw    = (const float*)d_in[10];
    const float* m_ao    = (const float*)d_in[11];
    const float* m_ag    = (const float*)d_in[12];
    const float* m_fg    = (const float*)d_in[13];
    const float* m_ex    = (const float*)d_in[14];
    const float* m_tk    = (const float*)d_in[15];
    const float* m_rb    = (const float*)d_in[16];
    const float* m_sup   = (const float*)d_in[17];
    const float* m_sdn   = (const float*)d_in[18];

    Scratch w;
    float* f = (float*)d_ws;
    w.qkv = f; f += 6291456;     // 2048*3072
    w.xi  = f; f += 2097152;
    w.h12 = f; f += 16777216;    // h1 | h2 ; also hup (dense) / hup_s (moe)
    w.t1  = w.h12 + 8388608;     // overlays h2 (dead after pmask)
    w.sc  = f; f += 16384;
    w.xA  = f; f += 2097152;
    w.xB  = f; f += 2097152;
    __bf16* b = (__bf16*)f;
    w.xn_bf    = b; b += 2097152;
    w.attnO_bf = b; b += 2097152;
    w.xf_bf    = b; b += 2097152;
    w.wbuf     = b; b += 19922944;
    w.gact_bf  = (__bf16*)w.qkv;            // overlays dead qkv
    w.gs_bf    = (__bf16*)w.qkv + 8388608;  // after gact region

    float* out = (float*)d_out;

    dense_layer_run(x, w.xA, d_aw, d_ao, d_up, d_down, d_ag, d_fg, doc, w, stream);
    const size_t EXL = (size_t)3 * LE * DIMM * DIM_E;
    moe_layer_run(w.xA, w.xB,
                  m_aw, m_ao, m_ag, m_fg,
                  m_ex, m_tk, m_rb, m_sup, m_sdn,
                  indices, values, doc, w, stream);
    moe_layer_run(w.xB, w.xA,
                  m_aw + (size_t)DIMM * 3 * DIMM, m_ao + (size_t)DIMM * DIMM,
                  m_ag + DIMM, m_fg + DIMM,
                  m_ex + EXL, m_tk + DIMM * LE, m_rb + LE,
                  m_sup + (size_t)DIMM * 2 * DIM_S, m_sdn + (size_t)DIM_S * DIMM,
                  indices + (size_t)NTOK * TOPK, values + (size_t)NTOK * TOPK,
                  doc, w, stream);
    dense_layer_run(w.xA, out,
                    d_aw + (size_t)DIMM * 3 * DIMM, d_ao + (size_t)DIMM * DIMM,
                    d_up + (size_t)DIMM * 2 * FFN_H, d_down + (size_t)FFN_H * DIMM,
                    d_ag + DIMM, d_fg + DIMM, doc, w, stream);
}

// Round 3
// 1747.164 us; speedup vs baseline: 7.3375x; 2.7781x over previous
//
#include <hip/hip_runtime.h>
#include <cmath>
#include <cstddef>
#include <cstdint>

#define DIMM   1024
#define HEADS  16
#define HEADD  64
#define FFN_H  4096
#define LE     8
#define TOPK   2
#define DIM_E  512
#define DIM_S  1024
#define NTOK   2048

typedef __bf16 bf16x8 __attribute__((ext_vector_type(8)));
typedef float  f32x4  __attribute__((ext_vector_type(4)));

union BF4 { __bf16 h[4]; uint2 u; };
union BF2 { __bf16 h[2]; uint32_t u; };

// ---------------------------------------------------------------------------
// RMSNorm -> bf16 output. One block (256 thr) per row of 1024.
// ---------------------------------------------------------------------------
__global__ __launch_bounds__(256) void rmsnorm_bf(
    const float* __restrict__ x, const float* __restrict__ g,
    __bf16* __restrict__ y)
{
    const int row = blockIdx.x;
    const int t = threadIdx.x;
    const float* xr = x + (size_t)row * DIMM;
    float4 v = *(const float4*)(xr + t * 4);
    float ss = v.x * v.x + v.y * v.y + v.z * v.z + v.w * v.w;
    #pragma unroll
    for (int off = 32; off > 0; off >>= 1) ss += __shfl_down(ss, off, 64);
    __shared__ float ws[4];
    if ((t & 63) == 0) ws[t >> 6] = ss;
    __syncthreads();
    const float tot = ws[0] + ws[1] + ws[2] + ws[3];
    const float scale = rsqrtf(tot * (1.0f / DIMM) + 1e-6f);
    const float4 gv = *(const float4*)(g + t * 4);
    BF4 o;
    o.h[0] = (__bf16)(v.x * scale * gv.x);
    o.h[1] = (__bf16)(v.y * scale * gv.y);
    o.h[2] = (__bf16)(v.z * scale * gv.z);
    o.h[3] = (__bf16)(v.w * scale * gv.w);
    *(uint2*)(y + (size_t)row * DIMM + t * 4) = o.u;
}

// ---------------------------------------------------------------------------
// bf16 MFMA GEMM: C[M,N] = A[M,K] @ BT[N,K]^T (+ add). fp32 out.
// ---------------------------------------------------------------------------
__global__ __launch_bounds__(256) void gemm_bf(
    const __bf16* __restrict__ A, const __bf16* __restrict__ BT,
    const float* __restrict__ add, float* __restrict__ C,
    int M, int N, int K)
{
    __shared__ __bf16 As[128 * 32];
    __shared__ __bf16 Bs[128 * 32];
    const int t = threadIdx.x;
    const int m0 = blockIdx.y * 128, n0 = blockIdx.x * 128;
    const int lane = t & 63;
    const int wv = t >> 6;
    const int mw = (wv >> 1) * 64, nw = (wv & 1) * 64;
    const int fr = lane & 15;
    const int fk = (lane >> 4) * 8;
    const int r0 = t >> 2;
    const int q0 = (t & 3) * 8;

    f32x4 acc[4][4];
    #pragma unroll
    for (int i = 0; i < 4; ++i)
        #pragma unroll
        for (int j = 0; j < 4; ++j) acc[i][j] = (f32x4){0.f, 0.f, 0.f, 0.f};

    for (int k0 = 0; k0 < K; k0 += 32) {
        const bf16x8 a0 = *(const bf16x8*)(A + (size_t)(m0 + r0) * K + k0 + q0);
        const bf16x8 a1 = *(const bf16x8*)(A + (size_t)(m0 + 64 + r0) * K + k0 + q0);
        const bf16x8 b0 = *(const bf16x8*)(BT + (size_t)(n0 + r0) * K + k0 + q0);
        const bf16x8 b1 = *(const bf16x8*)(BT + (size_t)(n0 + 64 + r0) * K + k0 + q0);
        __syncthreads();
        *(bf16x8*)&As[r0 * 32 + q0] = a0;
        *(bf16x8*)&As[(64 + r0) * 32 + q0] = a1;
        *(bf16x8*)&Bs[r0 * 32 + q0] = b0;
        *(bf16x8*)&Bs[(64 + r0) * 32 + q0] = b1;
        __syncthreads();
        bf16x8 af[4], bfr[4];
        #pragma unroll
        for (int i = 0; i < 4; ++i) {
            af[i]  = *(const bf16x8*)&As[(mw + i * 16 + fr) * 32 + fk];
            bfr[i] = *(const bf16x8*)&Bs[(nw + i * 16 + fr) * 32 + fk];
        }
        #pragma unroll
        for (int i = 0; i < 4; ++i)
            #pragma unroll
            for (int j = 0; j < 4; ++j)
                acc[i][j] = __builtin_amdgcn_mfma_f32_16x16x32_bf16(
                    af[i], bfr[j], acc[i][j], 0, 0, 0);
    }
    const int cn = lane & 15, cr = (lane >> 4) * 4;
    #pragma unroll
    for (int i = 0; i < 4; ++i)
        #pragma unroll
        for (int j = 0; j < 4; ++j)
            #pragma unroll
            for (int r = 0; r < 4; ++r) {
                const size_t off = (size_t)(m0 + mw + i * 16 + cr + r) * N
                                 + (n0 + nw + j * 16 + cn);
                C[off] = acc[i][j][r] + (add ? add[off] : 0.f);
            }
}

// ---------------------------------------------------------------------------
// Transpose + cast fp32[R][C] -> bf16[C][R], batched over blockIdx.z
// ---------------------------------------------------------------------------
__global__ __launch_bounds__(256) void transpose_cast(
    const float* __restrict__ in, __bf16* __restrict__ out, int R, int C)
{
    __shared__ float tile[32][33];
    const int bx = blockIdx.x * 32, by = blockIdx.y * 32;
    const size_t bz = (size_t)blockIdx.z * R * C;
    const int tx = threadIdx.x & 31, ty = threadIdx.x >> 5;
    const float* ip = in + bz;
    __bf16* op = out + bz;
    #pragma unroll
    for (int i = 0; i < 4; ++i)
        tile[ty + i * 8][tx] = ip[(size_t)(by + ty + i * 8) * C + bx + tx];
    __syncthreads();
    #pragma unroll
    for (int i = 0; i < 4; ++i)
        op[(size_t)(bx + ty + i * 8) * R + by + tx] = (__bf16)tile[tx][ty + i * 8];
}

// ---------------------------------------------------------------------------
// W2 [e][d][h] fp32 -> bf16 [d][e*512+h]
// ---------------------------------------------------------------------------
__global__ __launch_bounds__(256) void cast_w2(
    const float* __restrict__ in, __bf16* __restrict__ out)
{
    const int i = blockIdx.x * 256 + threadIdx.x;
    const int d = i >> 12, r = i & 4095;
    const int e = r >> 9, h = r & 511;
    out[i] = (__bf16)in[(size_t)e * (DIMM * DIM_E) + d * DIM_E + h];
}

// ---------------------------------------------------------------------------
// Rotary in-place on q and k sections of qkv [NTOK][3072] (fp32)
// ---------------------------------------------------------------------------
__global__ __launch_bounds__(256) void rotary_kernel(float* __restrict__ qkv)
{
    const int i = blockIdx.x * 256 + threadIdx.x;
    const int s = i >> 9;
    const int rem = i & 511;
    const int h = rem >> 5;
    const int j = rem & 31;
    const float inv_freq = __expf(-(float)j * (9.210340371976184f / 32.f));
    const float f = (float)s * inv_freq;
    float sn, cs;
    sincosf(f, &sn, &cs);
    float* base = qkv + (size_t)s * 3072 + h * 64 + j;
    const float q1 = base[0], q2 = base[32];
    base[0]  = q1 * cs + q2 * sn;
    base[32] = -q1 * sn + q2 * cs;
    const float k1 = base[1024], k2 = base[1024 + 32];
    base[1024]      = k1 * cs + k2 * sn;
    base[1024 + 32] = -k1 * sn + k2 * cs;
}

// ---------------------------------------------------------------------------
// MFMA flash attention, causal + same-doc mask. fp32 qkv in, bf16 out.
// Grid (HEADS, NTOK/64); block 256 = 4 waves; wave w handles 16 q-rows.
// ---------------------------------------------------------------------------
#define KS_STRIDE 72
#define VT_STRIDE 72
#define PW_STRIDE 36
#define LOG2E 1.4426950408889634f

__global__ __launch_bounds__(256) void attn_mfma(
    const float* __restrict__ qkv, const int* __restrict__ doc,
    __bf16* __restrict__ out)
{
    const int h = blockIdx.x;
    const int qb = blockIdx.y;
    const int t = threadIdx.x;
    const int wv = t >> 6, lane = t & 63;
    const int l15 = lane & 15, lhi = lane >> 4;
    const int q0w = qb * 64 + wv * 16;

    __shared__ __bf16 Ks[64 * KS_STRIDE];
    __shared__ __bf16 Vt[64 * VT_STRIDE];
    __shared__ float  Pw[4][16 * PW_STRIDE];
    __shared__ int    docs[64];

    // Q fragments (A-layout: m=l15, k=lhi*8+j), pre-scaled by 1/8
    bf16x8 qf[2];
    {
        const float* qrow = qkv + (size_t)(q0w + l15) * 3072 + h * 64 + lhi * 8;
        #pragma unroll
        for (int db = 0; db < 2; ++db) {
            const float4 v0 = *(const float4*)(qrow + db * 32);
            const float4 v1 = *(const float4*)(qrow + db * 32 + 4);
            bf16x8 f;
            f[0] = (__bf16)(v0.x * 0.125f); f[1] = (__bf16)(v0.y * 0.125f);
            f[2] = (__bf16)(v0.z * 0.125f); f[3] = (__bf16)(v0.w * 0.125f);
            f[4] = (__bf16)(v1.x * 0.125f); f[5] = (__bf16)(v1.y * 0.125f);
            f[6] = (__bf16)(v1.z * 0.125f); f[7] = (__bf16)(v1.w * 0.125f);
            qf[db] = f;
        }
    }
    int myDoc[4];
    #pragma unroll
    for (int rg = 0; rg < 4; ++rg) myDoc[rg] = doc[q0w + lhi * 4 + rg];

    float mrow[4] = {-INFINITY, -INFINITY, -INFINITY, -INFINITY};
    float lrow[4] = {0.f, 0.f, 0.f, 0.f};
    f32x4 oacc[4];
    #pragma unroll
    for (int nb = 0; nb < 4; ++nb) oacc[nb] = (f32x4){0.f, 0.f, 0.f, 0.f};

    const int docQ0 = doc[qb * 64];
    const int ntiles = qb + 1;

    for (int kt = 0; kt < ntiles; ++kt) {
        if (doc[kt * 64 + 63] < docQ0) continue;   // block-uniform doc skip
        __syncthreads();
        {   // stage K [key][dim] bf16
            const int key = t >> 2, dof = (t & 3) * 16;
            const float* kr = qkv + (size_t)(kt * 64 + key) * 3072 + 1024 + h * 64 + dof;
            float kv[16];
            *(float4*)&kv[0]  = *(const float4*)(kr + 0);
            *(float4*)&kv[4]  = *(const float4*)(kr + 4);
            *(float4*)&kv[8]  = *(const float4*)(kr + 8);
            *(float4*)&kv[12] = *(const float4*)(kr + 12);
            bf16x8 p0, p1;
            #pragma unroll
            for (int j = 0; j < 8; ++j) { p0[j] = (__bf16)kv[j]; p1[j] = (__bf16)kv[8 + j]; }
            *(bf16x8*)&Ks[key * KS_STRIDE + dof] = p0;
            *(bf16x8*)&Ks[key * KS_STRIDE + dof + 8] = p1;
            // stage V^T [dim][key] bf16, 2 keys x 8 dims per thread
            const int k2 = (t & 31) * 2, df = (t >> 5) * 8;
            const float* vr0 = qkv + (size_t)(kt * 64 + k2) * 3072 + 2048 + h * 64 + df;
            float va[8], vb[8];
            *(float4*)&va[0] = *(const float4*)(vr0 + 0);
            *(float4*)&va[4] = *(const float4*)(vr0 + 4);
            *(float4*)&vb[0] = *(const float4*)(vr0 + 3072);
            *(float4*)&vb[4] = *(const float4*)(vr0 + 3076);
            #pragma unroll
            for (int d = 0; d < 8; ++d) {
                BF2 wpk;
                wpk.h[0] = (__bf16)va[d];
                wpk.h[1] = (__bf16)vb[d];
                *(uint32_t*)&Vt[(df + d) * VT_STRIDE + k2] = wpk.u;
            }
            if (t < 64) docs[t] = doc[kt * 64 + t];
        }
        __syncthreads();

        #pragma unroll
        for (int g = 0; g < 2; ++g) {
            // QK^T: two 16-key subtiles
            f32x4 s[2];
            #pragma unroll
            for (int sg = 0; sg < 2; ++sg) {
                const int keyloc = g * 32 + sg * 16;
                const bf16x8 kf0 = *(const bf16x8*)&Ks[(keyloc + l15) * KS_STRIDE + lhi * 8];
                const bf16x8 kf1 = *(const bf16x8*)&Ks[(keyloc + l15) * KS_STRIDE + 32 + lhi * 8];
                f32x4 a = (f32x4){0.f, 0.f, 0.f, 0.f};
                a = __builtin_amdgcn_mfma_f32_16x16x32_bf16(qf[0], kf0, a, 0, 0, 0);
                a = __builtin_amdgcn_mfma_f32_16x16x32_bf16(qf[1], kf1, a, 0, 0, 0);
                s[sg] = a;
            }
            // mask + online softmax (rows r = q0w + lhi*4 + rg)
            float sv0[4], sv1[4], cmax[4];
            #pragma unroll
            for (int rg = 0; rg < 4; ++rg) {
                const int r = q0w + lhi * 4 + rg;
                const int key0 = kt * 64 + g * 32 + l15;
                const bool v0 = (key0 <= r) && (docs[g * 32 + l15] == myDoc[rg]);
                const bool v1 = (key0 + 16 <= r) && (docs[g * 32 + 16 + l15] == myDoc[rg]);
                sv0[rg] = v0 ? s[0][rg] : -INFINITY;
                sv1[rg] = v1 ? s[1][rg] : -INFINITY;
                cmax[rg] = fmaxf(sv0[rg], sv1[rg]);
            }
            #pragma unroll
            for (int off = 1; off < 16; off <<= 1)
                #pragma unroll
                for (int rg = 0; rg < 4; ++rg)
                    cmax[rg] = fmaxf(cmax[rg], __shfl_xor(cmax[rg], off, 64));
            float alpha[4], p0[4], p1[4], rsum[4];
            #pragma unroll
            for (int rg = 0; rg < 4; ++rg) {
                const float mn = fmaxf(mrow[rg], cmax[rg]);
                alpha[rg] = (mn == -INFINITY) ? 1.f : exp2f((mrow[rg] - mn) * LOG2E);
                p0[rg] = (sv0[rg] == -INFINITY) ? 0.f : exp2f((sv0[rg] - mn) * LOG2E);
                p1[rg] = (sv1[rg] == -INFINITY) ? 0.f : exp2f((sv1[rg] - mn) * LOG2E);
                rsum[rg] = p0[rg] + p1[rg];
                mrow[rg] = mn;
            }
            #pragma unroll
            for (int off = 1; off < 16; off <<= 1)
                #pragma unroll
                for (int rg = 0; rg < 4; ++rg)
                    rsum[rg] += __shfl_xor(rsum[rg], off, 64);
            #pragma unroll
            for (int rg = 0; rg < 4; ++rg)
                lrow[rg] = lrow[rg] * alpha[rg] + rsum[rg];
            #pragma unroll
            for (int nb = 0; nb < 4; ++nb)
                #pragma unroll
                for (int rg = 0; rg < 4; ++rg)
                    oacc[nb][rg] *= alpha[rg];
            // P: C-layout -> LDS fp32 -> A-layout bf16
            float* pp = &Pw[wv][0];
            #pragma unroll
            for (int rg = 0; rg < 4; ++rg) {
                pp[(lhi * 4 + rg) * PW_STRIDE + l15] = p0[rg];
                pp[(lhi * 4 + rg) * PW_STRIDE + 16 + l15] = p1[rg];
            }
            const f32x4 pa = *(const f32x4*)&pp[l15 * PW_STRIDE + lhi * 8];
            const f32x4 pb = *(const f32x4*)&pp[l15 * PW_STRIDE + lhi * 8 + 4];
            bf16x8 pf;
            pf[0] = (__bf16)pa[0]; pf[1] = (__bf16)pa[1];
            pf[2] = (__bf16)pa[2]; pf[3] = (__bf16)pa[3];
            pf[4] = (__bf16)pb[0]; pf[5] = (__bf16)pb[1];
            pf[6] = (__bf16)pb[2]; pf[7] = (__bf16)pb[3];
            // PV: 4 dim-blocks, K = 32 keys
            #pragma unroll
            for (int nb = 0; nb < 4; ++nb) {
                const bf16x8 vf = *(const bf16x8*)&Vt[(nb * 16 + l15) * VT_STRIDE + g * 32 + lhi * 8];
                oacc[nb] = __builtin_amdgcn_mfma_f32_16x16x32_bf16(pf, vf, oacc[nb], 0, 0, 0);
            }
        }
    }
    float inv[4];
    #pragma unroll
    for (int rg = 0; rg < 4; ++rg) inv[rg] = 1.f / lrow[rg];
    #pragma unroll
    for (int nb = 0; nb < 4; ++nb)
        #pragma unroll
        for (int rg = 0; rg < 4; ++rg)
            out[(size_t)(q0w + lhi * 4 + rg) * DIMM + h * 64 + nb * 16 + l15] =
                (__bf16)(oacc[nb][rg] * inv[rg]);
}

// ---------------------------------------------------------------------------
// SwiGLU: g[n][j] = silu(h[n][j]) * h[n][j+H], H=1<<shift; bf16 out, 4/thread
// ---------------------------------------------------------------------------
__global__ __launch_bounds__(256) void swiglu_bf(
    const float* __restrict__ h, __bf16* __restrict__ g, int shift)
{
    const int i4 = blockIdx.x * 256 + threadIdx.x;
    const int H = 1 << shift;
    const int n = (i4 * 4) >> shift;
    const int j = (i4 * 4) & (H - 1);
    const float* hr = h + ((size_t)n << (shift + 1));
    const float4 a = *(const float4*)(hr + j);
    const float4 b = *(const float4*)(hr + H + j);
    BF4 o;
    o.h[0] = (__bf16)((a.x / (1.f + __expf(-a.x))) * b.x);
    o.h[1] = (__bf16)((a.y / (1.f + __expf(-a.y))) * b.y);
    o.h[2] = (__bf16)((a.z / (1.f + __expf(-a.z))) * b.z);
    o.h[3] = (__bf16)((a.w / (1.f + __expf(-a.w))) * b.w);
    *(uint2*)(g + (size_t)i4 * 4) = o.u;
}

// ---------------------------------------------------------------------------
// p~[n][e*512+h] = silu(h1)*h2 * sc[n][e]
// ---------------------------------------------------------------------------
__global__ __launch_bounds__(256) void pmask_bf(
    const float* __restrict__ h1, const float* __restrict__ h2,
    const float* __restrict__ sc, __bf16* __restrict__ p)
{
    const int i4 = blockIdx.x * 256 + threadIdx.x;
    const int n = i4 >> 10;
    const int e = (i4 & 1023) >> 7;
    const float s = sc[n * LE + e];
    const float4 a = *(const float4*)(h1 + (size_t)i4 * 4);
    const float4 b = *(const float4*)(h2 + (size_t)i4 * 4);
    BF4 o;
    o.h[0] = (__bf16)((a.x / (1.f + __expf(-a.x))) * b.x * s);
    o.h[1] = (__bf16)((a.y / (1.f + __expf(-a.y))) * b.y * s);
    o.h[2] = (__bf16)((a.z / (1.f + __expf(-a.z))) * b.z * s);
    o.h[3] = (__bf16)((a.w / (1.f + __expf(-a.w))) * b.w * s);
    *(uint2*)(p + (size_t)i4 * 4) = o.u;
}

// ---------------------------------------------------------------------------
// Router: sc[n][e] dense (0 for unselected)
// ---------------------------------------------------------------------------
__global__ __launch_bounds__(64) void router_bf(
    const __bf16* __restrict__ xf, const float* __restrict__ tkeys,
    const float* __restrict__ rbias, const int* __restrict__ idx,
    const float* __restrict__ vals, float* __restrict__ sc)
{
    const int n = blockIdx.x;
    const int t = threadIdx.x;
    const int e0 = idx[n * 2 + 0], e1 = idx[n * 2 + 1];
    float a0 = 0.f, a1 = 0.f;
    for (int d = t; d < DIMM; d += 64) {
        const float xv = (float)xf[(size_t)n * DIMM + d];
        a0 += xv * tkeys[d * LE + e0];
        a1 += xv * tkeys[d * LE + e1];
    }
    #pragma unroll
    for (int off = 32; off > 0; off >>= 1) {
        a0 += __shfl_down(a0, off, 64);
        a1 += __shfl_down(a1, off, 64);
    }
    if (t == 0) {
        const float v0 = vals[n * 2 + 0] + a0 + rbias[e0];
        const float v1 = vals[n * 2 + 1] + a1 + rbias[e1];
        const float s0 = 1.f / (1.f + __expf(-v0));
        const float s1 = 1.f / (1.f + __expf(-v1));
        const float inv = 1.f / (s0 + s1);
        float r[LE];
        #pragma unroll
        for (int e = 0; e < LE; ++e) r[e] = 0.f;
        r[e0] += s0 * inv;
        r[e1] += s1 * inv;
        #pragma unroll
        for (int e = 0; e < LE; ++e) sc[n * LE + e] = r[e];
    }
}

// ---------------------------------------------------------------------------
// Host orchestration
// ---------------------------------------------------------------------------
struct Scratch {
    float *qkv, *xi, *h12, *t1, *sc, *xA, *xB;
    __bf16 *xn_bf, *attnO_bf, *xf_bf, *wbuf, *gact_bf, *gs_bf;
};

static void attn_block(const float* x_in, const __bf16* awT, const __bf16* aoT,
                       const float* ag, const int* doc, Scratch& w, hipStream_t s)
{
    rmsnorm_bf<<<NTOK, 256, 0, s>>>(x_in, ag, w.xn_bf);
    gemm_bf<<<dim3(24, 16), 256, 0, s>>>(w.xn_bf, awT, nullptr, w.qkv, NTOK, 3072, 1024);
    rotary_kernel<<<(NTOK * 512) / 256, 256, 0, s>>>(w.qkv);
    attn_mfma<<<dim3(HEADS, NTOK / 64), 256, 0, s>>>(w.qkv, doc, w.attnO_bf);
    gemm_bf<<<dim3(8, 16), 256, 0, s>>>(w.attnO_bf, aoT, x_in, w.xi, NTOK, 1024, 1024);
}

static void dense_layer_run(const float* x_in, float* x_out,
                            const float* aw, const float* ao,
                            const float* up, const float* down,
                            const float* ag, const float* fg,
                            const int* doc, Scratch& w, hipStream_t s)
{
    __bf16* awT = w.wbuf;
    __bf16* aoT = w.wbuf + 3145728;
    __bf16* upT = w.wbuf + 4194304;
    __bf16* dnT = w.wbuf + 12582912;
    transpose_cast<<<dim3(96, 32, 1), 256, 0, s>>>(aw, awT, 1024, 3072);
    transpose_cast<<<dim3(32, 32, 1), 256, 0, s>>>(ao, aoT, 1024, 1024);
    transpose_cast<<<dim3(256, 32, 1), 256, 0, s>>>(up, upT, 1024, 8192);
    transpose_cast<<<dim3(32, 128, 1), 256, 0, s>>>(down, dnT, 4096, 1024);
    attn_block(x_in, awT, aoT, ag, doc, w, s);
    rmsnorm_bf<<<NTOK, 256, 0, s>>>(w.xi, fg, w.xf_bf);
    gemm_bf<<<dim3(64, 16), 256, 0, s>>>(w.xf_bf, upT, nullptr, w.h12, NTOK, 8192, 1024);
    swiglu_bf<<<(NTOK * FFN_H / 4) / 256, 256, 0, s>>>(w.h12, w.gact_bf, 12);
    gemm_bf<<<dim3(8, 16), 256, 0, s>>>(w.gact_bf, dnT, w.xi, x_out, NTOK, 1024, 4096);
}

static void moe_layer_run(const float* x_in, float* x_out,
                          const float* aw, const float* ao,
                          const float* ag, const float* fg,
                          const float* experts, const float* tkeys,
                          const float* rbias, const float* sup,
                          const float* sdn, const int* idx, const float* vals,
                          const int* doc, Scratch& w, hipStream_t s)
{
    __bf16* awT  = w.wbuf;
    __bf16* aoT  = w.wbuf + 3145728;
    __bf16* w0T  = w.wbuf + 4194304;
    __bf16* w1T  = w.wbuf + 8388608;
    __bf16* w2c  = w.wbuf + 12582912;
    __bf16* supT = w.wbuf + 16777216;
    __bf16* sdnT = w.wbuf + 18874368;
    const size_t EW = (size_t)LE * DIMM * DIM_E;
    transpose_cast<<<dim3(96, 32, 1), 256, 0, s>>>(aw, awT, 1024, 3072);
    transpose_cast<<<dim3(32, 32, 1), 256, 0, s>>>(ao, aoT, 1024, 1024);
    transpose_cast<<<dim3(16, 32, 8), 256, 0, s>>>(experts, w0T, 1024, 512);
    transpose_cast<<<dim3(16, 32, 8), 256, 0, s>>>(experts + EW, w1T, 1024, 512);
    cast_w2<<<16384, 256, 0, s>>>(experts + 2 * EW, w2c);
    transpose_cast<<<dim3(64, 32, 1), 256, 0, s>>>(sup, supT, 1024, 2048);
    transpose_cast<<<dim3(32, 32, 1), 256, 0, s>>>(sdn, sdnT, 1024, 1024);

    attn_block(x_in, awT, aoT, ag, doc, w, s);
    rmsnorm_bf<<<NTOK, 256, 0, s>>>(w.xi, fg, w.xf_bf);
    router_bf<<<NTOK, 64, 0, s>>>(w.xf_bf, tkeys, rbias, idx, vals, w.sc);
    float* h1 = w.h12;
    float* h2 = w.h12 + 8388608;
    gemm_bf<<<dim3(32, 16), 256, 0, s>>>(w.xf_bf, w0T, nullptr, h1, NTOK, 4096, 1024);
    gemm_bf<<<dim3(32, 16), 256, 0, s>>>(w.xf_bf, w1T, nullptr, h2, NTOK, 4096, 1024);
    pmask_bf<<<(NTOK * 4096 / 4) / 256, 256, 0, s>>>(h1, h2, w.sc, w.gact_bf);
    gemm_bf<<<dim3(16, 16), 256, 0, s>>>(w.xf_bf, supT, nullptr, w.h12, NTOK, 2048, 1024);
    swiglu_bf<<<(NTOK * DIM_S / 4) / 256, 256, 0, s>>>(w.h12, w.gs_bf, 10);
    gemm_bf<<<dim3(8, 16), 256, 0, s>>>(w.gs_bf, sdnT, w.xi, w.t1, NTOK, 1024, 1024);
    gemm_bf<<<dim3(8, 16), 256, 0, s>>>(w.gact_bf, w2c, w.t1, x_out, NTOK, 1024, 4096);
}

extern "C" void kernel_launch(void* const* d_in, const int* in_sizes, int n_in,
                              void* d_out, int out_size, void* d_ws, size_t ws_size,
                              hipStream_t stream)
{
    (void)in_sizes; (void)n_in; (void)out_size; (void)ws_size;
    const float* x       = (const float*)d_in[0];
    const int*   doc     = (const int*)d_in[1];
    const int*   indices = (const int*)d_in[2];
    const float* values  = (const float*)d_in[3];
    const float* d_aw    = (const float*)d_in[4];
    const float* d_ao    = (const float*)d_in[5];
    const float* d_up    = (const float*)d_in[6];
    const float* d_down  = (const float*)d_in[7];
    const float* d_ag    = (const float*)d_in[8];
    const float* d_fg    = (const float*)d_in[9];
    const float* m_aw    = (const float*)d_in[10];
    const float* m_ao    = (const float*)d_in[11];
    const float* m_ag    = (const float*)d_in[12];
    const float* m_fg    = (const float*)d_in[13];
    const float* m_ex    = (const float*)d_in[14];
    const float* m_tk    = (const float*)d_in[15];
    const float* m_rb    = (const float*)d_in[16];
    const float* m_sup   = (const float*)d_in[17];
    const float* m_sdn   = (const float*)d_in[18];

    Scratch w;
    float* f = (float*)d_ws;
    w.qkv = f; f += 6291456;
    w.xi  = f; f += 2097152;
    w.h12 = f; f += 16777216;
    w.t1  = w.h12 + 8388608;
    w.sc  = f; f += 16384;
    w.xA  = f; f += 2097152;
    w.xB  = f; f += 2097152;
    __bf16* b = (__bf16*)f;
    w.xn_bf    = b; b += 2097152;
    w.attnO_bf = b; b += 2097152;
    w.xf_bf    = b; b += 2097152;
    w.wbuf     = b; b += 19922944;
    w.gact_bf  = (__bf16*)w.qkv;
    w.gs_bf    = (__bf16*)w.qkv + 8388608;

    float* out = (float*)d_out;

    dense_layer_run(x, w.xA, d_aw, d_ao, d_up, d_down, d_ag, d_fg, doc, w, stream);
    const size_t EXL = (size_t)3 * LE * DIMM * DIM_E;
    moe_layer_run(w.xA, w.xB,
                  m_aw, m_ao, m_ag, m_fg,
                  m_ex, m_tk, m_rb, m_sup, m_sdn,
                  indices, values, doc, w, stream);
    moe_layer_run(w.xB, w.xA,
                  m_aw + (size_t)DIMM * 3 * DIMM, m_ao + (size_t)DIMM * DIMM,
                  m_ag + DIMM, m_fg + DIMM,
                  m_ex + EXL, m_tk + DIMM * LE, m_rb + LE,
                  m_sup + (size_t)DIMM * 2 * DIM_S, m_sdn + (size_t)DIM_S * DIMM,
                  indices + (size_t)NTOK * TOPK, values + (size_t)NTOK * TOPK,
                  doc, w, stream);
    dense_layer_run(w.xA, out,
                    d_aw + (size_t)DIMM * 3 * DIMM, d_ao + (size_t)DIMM * DIMM,
                    d_up + (size_t)DIMM * 2 * FFN_H, d_down + (size_t)FFN_H * DIMM,
                    d_ag + DIMM, d_fg + DIMM, doc, w, stream);
}

// Round 4
// 1650.180 us; speedup vs baseline: 7.7687x; 1.0588x over previous
//
#include <hip/hip_runtime.h>
#include <cmath>
#include <cstddef>
#include <cstdint>

#define DIMM   1024
#define HEADS  16
#define HEADD  64
#define FFN_H  4096
#define LE     8
#define TOPK   2
#define DIM_E  512
#define DIM_S  1024
#define NTOK   2048

typedef __bf16 bf16x8 __attribute__((ext_vector_type(8)));
typedef float  f32x4  __attribute__((ext_vector_type(4)));

union BF4 { __bf16 h[4]; uint2 u; };
union BF2 { __bf16 h[2]; uint32_t u; };

// async global->LDS, 16B per lane (wave-uniform base + lane*16 layout)
__device__ __forceinline__ void ldg_lds16(const __bf16* g, __bf16* l) {
    __builtin_amdgcn_global_load_lds(
        (const __attribute__((address_space(1))) uint32_t*)g,
        (__attribute__((address_space(3))) uint32_t*)l, 16, 0, 0);
}

// ---------------------------------------------------------------------------
// RMSNorm -> bf16 output. One block (256 thr) per row of 1024.
// ---------------------------------------------------------------------------
__global__ __launch_bounds__(256) void rmsnorm_bf(
    const float* __restrict__ x, const float* __restrict__ g,
    __bf16* __restrict__ y)
{
    const int row = blockIdx.x;
    const int t = threadIdx.x;
    const float* xr = x + (size_t)row * DIMM;
    float4 v = *(const float4*)(xr + t * 4);
    float ss = v.x * v.x + v.y * v.y + v.z * v.z + v.w * v.w;
    #pragma unroll
    for (int off = 32; off > 0; off >>= 1) ss += __shfl_down(ss, off, 64);
    __shared__ float ws[4];
    if ((t & 63) == 0) ws[t >> 6] = ss;
    __syncthreads();
    const float tot = ws[0] + ws[1] + ws[2] + ws[3];
    const float scale = rsqrtf(tot * (1.0f / DIMM) + 1e-6f);
    const float4 gv = *(const float4*)(g + t * 4);
    BF4 o;
    o.h[0] = (__bf16)(v.x * scale * gv.x);
    o.h[1] = (__bf16)(v.y * scale * gv.y);
    o.h[2] = (__bf16)(v.z * scale * gv.z);
    o.h[3] = (__bf16)(v.w * scale * gv.w);
    *(uint2*)(y + (size_t)row * DIMM + t * 4) = o.u;
}

// ---------------------------------------------------------------------------
// bf16 MFMA GEMM, async LDS staging (m97 structure).
// C[M,N] = A[M,K] @ BT[N,K]^T (+ add, float-out only). OutT = float | __bf16.
// ---------------------------------------------------------------------------
template <typename OutT>
__global__ __launch_bounds__(256) void gemm_bf_t(
    const __bf16* __restrict__ A, const __bf16* __restrict__ BT,
    const float* __restrict__ add, OutT* __restrict__ C,
    int M, int N, int K)
{
    __shared__ __bf16 As[128 * 32];   // [row][k] 64B/row — lane order = t*16B
    __shared__ __bf16 Bs[128 * 32];
    const int t = threadIdx.x;
    const int m0 = blockIdx.y * 128, n0 = blockIdx.x * 128;
    const int lane = t & 63;
    const int wv = t >> 6;
    const int mw = (wv >> 1) * 64, nw = (wv & 1) * 64;
    const int fr = lane & 15;
    const int fk = (lane >> 4) * 8;
    const int r0 = t >> 2;
    const int q0 = (t & 3) * 8;

    const __bf16* gA0 = A + (size_t)(m0 + r0) * K + q0;
    const __bf16* gA1 = A + (size_t)(m0 + 64 + r0) * K + q0;
    const __bf16* gB0 = BT + (size_t)(n0 + r0) * K + q0;
    const __bf16* gB1 = BT + (size_t)(n0 + 64 + r0) * K + q0;
    __bf16* lA0 = &As[r0 * 32 + q0];
    __bf16* lA1 = &As[(64 + r0) * 32 + q0];
    __bf16* lB0 = &Bs[r0 * 32 + q0];
    __bf16* lB1 = &Bs[(64 + r0) * 32 + q0];

    f32x4 acc[4][4];
    #pragma unroll
    for (int i = 0; i < 4; ++i)
        #pragma unroll
        for (int j = 0; j < 4; ++j) acc[i][j] = (f32x4){0.f, 0.f, 0.f, 0.f};

    for (int k0 = 0; k0 < K; k0 += 32) {
        __syncthreads();
        ldg_lds16(gA0 + k0, lA0);
        ldg_lds16(gA1 + k0, lA1);
        ldg_lds16(gB0 + k0, lB0);
        ldg_lds16(gB1 + k0, lB1);
        __syncthreads();
        bf16x8 af[4], bfr[4];
        #pragma unroll
        for (int i = 0; i < 4; ++i) {
            af[i]  = *(const bf16x8*)&As[(mw + i * 16 + fr) * 32 + fk];
            bfr[i] = *(const bf16x8*)&Bs[(nw + i * 16 + fr) * 32 + fk];
        }
        #pragma unroll
        for (int i = 0; i < 4; ++i)
            #pragma unroll
            for (int j = 0; j < 4; ++j)
                acc[i][j] = __builtin_amdgcn_mfma_f32_16x16x32_bf16(
                    af[i], bfr[j], acc[i][j], 0, 0, 0);
    }
    const int cn = lane & 15, cr = (lane >> 4) * 4;
    #pragma unroll
    for (int i = 0; i < 4; ++i)
        #pragma unroll
        for (int j = 0; j < 4; ++j)
            #pragma unroll
            for (int r = 0; r < 4; ++r) {
                const size_t off = (size_t)(m0 + mw + i * 16 + cr + r) * N
                                 + (n0 + nw + j * 16 + cn);
                if constexpr (__is_same(OutT, float))
                    C[off] = acc[i][j][r] + (add ? add[off] : 0.f);
                else
                    C[off] = (__bf16)acc[i][j][r];
            }
}

// ---------------------------------------------------------------------------
// Transpose + cast fp32[R][C] -> bf16[C][R], batched over blockIdx.z
// ---------------------------------------------------------------------------
__global__ __launch_bounds__(256) void transpose_cast(
    const float* __restrict__ in, __bf16* __restrict__ out, int R, int C)
{
    __shared__ float tile[32][33];
    const int bx = blockIdx.x * 32, by = blockIdx.y * 32;
    const size_t bz = (size_t)blockIdx.z * R * C;
    const int tx = threadIdx.x & 31, ty = threadIdx.x >> 5;
    const float* ip = in + bz;
    __bf16* op = out + bz;
    #pragma unroll
    for (int i = 0; i < 4; ++i)
        tile[ty + i * 8][tx] = ip[(size_t)(by + ty + i * 8) * C + bx + tx];
    __syncthreads();
    #pragma unroll
    for (int i = 0; i < 4; ++i)
        op[(size_t)(bx + ty + i * 8) * R + by + tx] = (__bf16)tile[tx][ty + i * 8];
}

// ---------------------------------------------------------------------------
// W2 [e][d][h] fp32 -> bf16 [d][e*512+h]
// ---------------------------------------------------------------------------
__global__ __launch_bounds__(256) void cast_w2(
    const float* __restrict__ in, __bf16* __restrict__ out)
{
    const int i = blockIdx.x * 256 + threadIdx.x;
    const int d = i >> 12, r = i & 4095;
    const int e = r >> 9, h = r & 511;
    out[i] = (__bf16)in[(size_t)e * (DIMM * DIM_E) + d * DIM_E + h];
}

// ---------------------------------------------------------------------------
// Rotary in-place on q and k sections of qkv [NTOK][3072] (fp32)
// ---------------------------------------------------------------------------
__global__ __launch_bounds__(256) void rotary_kernel(float* __restrict__ qkv)
{
    const int i = blockIdx.x * 256 + threadIdx.x;
    const int s = i >> 9;
    const int rem = i & 511;
    const int h = rem >> 5;
    const int j = rem & 31;
    const float inv_freq = __expf(-(float)j * (9.210340371976184f / 32.f));
    const float f = (float)s * inv_freq;
    float sn, cs;
    sincosf(f, &sn, &cs);
    float* base = qkv + (size_t)s * 3072 + h * 64 + j;
    const float q1 = base[0], q2 = base[32];
    base[0]  = q1 * cs + q2 * sn;
    base[32] = -q1 * sn + q2 * cs;
    const float k1 = base[1024], k2 = base[1024 + 32];
    base[1024]      = k1 * cs + k2 * sn;
    base[1024 + 32] = -k1 * sn + k2 * cs;
}

// ---------------------------------------------------------------------------
// MFMA flash attention, causal + same-doc mask. fp32 qkv in, bf16 out.
// ---------------------------------------------------------------------------
#define KS_STRIDE 72
#define VT_STRIDE 72
#define PW_STRIDE 36
#define LOG2E 1.4426950408889634f

__global__ __launch_bounds__(256) void attn_mfma(
    const float* __restrict__ qkv, const int* __restrict__ doc,
    __bf16* __restrict__ out)
{
    const int h = blockIdx.x;
    const int qb = blockIdx.y;
    const int t = threadIdx.x;
    const int wv = t >> 6, lane = t & 63;
    const int l15 = lane & 15, lhi = lane >> 4;
    const int q0w = qb * 64 + wv * 16;

    __shared__ __bf16 Ks[64 * KS_STRIDE];
    __shared__ __bf16 Vt[64 * VT_STRIDE];
    __shared__ float  Pw[4][16 * PW_STRIDE];
    __shared__ int    docs[64];

    bf16x8 qf[2];
    {
        const float* qrow = qkv + (size_t)(q0w + l15) * 3072 + h * 64 + lhi * 8;
        #pragma unroll
        for (int db = 0; db < 2; ++db) {
            const float4 v0 = *(const float4*)(qrow + db * 32);
            const float4 v1 = *(const float4*)(qrow + db * 32 + 4);
            bf16x8 f;
            f[0] = (__bf16)(v0.x * 0.125f); f[1] = (__bf16)(v0.y * 0.125f);
            f[2] = (__bf16)(v0.z * 0.125f); f[3] = (__bf16)(v0.w * 0.125f);
            f[4] = (__bf16)(v1.x * 0.125f); f[5] = (__bf16)(v1.y * 0.125f);
            f[6] = (__bf16)(v1.z * 0.125f); f[7] = (__bf16)(v1.w * 0.125f);
            qf[db] = f;
        }
    }
    int myDoc[4];
    #pragma unroll
    for (int rg = 0; rg < 4; ++rg) myDoc[rg] = doc[q0w + lhi * 4 + rg];

    float mrow[4] = {-INFINITY, -INFINITY, -INFINITY, -INFINITY};
    float lrow[4] = {0.f, 0.f, 0.f, 0.f};
    f32x4 oacc[4];
    #pragma unroll
    for (int nb = 0; nb < 4; ++nb) oacc[nb] = (f32x4){0.f, 0.f, 0.f, 0.f};

    const int docQ0 = doc[qb * 64];
    const int ntiles = qb + 1;

    for (int kt = 0; kt < ntiles; ++kt) {
        if (doc[kt * 64 + 63] < docQ0) continue;
        __syncthreads();
        {
            const int key = t >> 2, dof = (t & 3) * 16;
            const float* kr = qkv + (size_t)(kt * 64 + key) * 3072 + 1024 + h * 64 + dof;
            float kv[16];
            *(float4*)&kv[0]  = *(const float4*)(kr + 0);
            *(float4*)&kv[4]  = *(const float4*)(kr + 4);
            *(float4*)&kv[8]  = *(const float4*)(kr + 8);
            *(float4*)&kv[12] = *(const float4*)(kr + 12);
            bf16x8 p0, p1;
            #pragma unroll
            for (int j = 0; j < 8; ++j) { p0[j] = (__bf16)kv[j]; p1[j] = (__bf16)kv[8 + j]; }
            *(bf16x8*)&Ks[key * KS_STRIDE + dof] = p0;
            *(bf16x8*)&Ks[key * KS_STRIDE + dof + 8] = p1;
            const int k2 = (t & 31) * 2, df = (t >> 5) * 8;
            const float* vr0 = qkv + (size_t)(kt * 64 + k2) * 3072 + 2048 + h * 64 + df;
            float va[8], vb[8];
            *(float4*)&va[0] = *(const float4*)(vr0 + 0);
            *(float4*)&va[4] = *(const float4*)(vr0 + 4);
            *(float4*)&vb[0] = *(const float4*)(vr0 + 3072);
            *(float4*)&vb[4] = *(const float4*)(vr0 + 3076);
            #pragma unroll
            for (int d = 0; d < 8; ++d) {
                BF2 wpk;
                wpk.h[0] = (__bf16)va[d];
                wpk.h[1] = (__bf16)vb[d];
                *(uint32_t*)&Vt[(df + d) * VT_STRIDE + k2] = wpk.u;
            }
            if (t < 64) docs[t] = doc[kt * 64 + t];
        }
        __syncthreads();

        #pragma unroll
        for (int g = 0; g < 2; ++g) {
            f32x4 s[2];
            #pragma unroll
            for (int sg = 0; sg < 2; ++sg) {
                const int keyloc = g * 32 + sg * 16;
                const bf16x8 kf0 = *(const bf16x8*)&Ks[(keyloc + l15) * KS_STRIDE + lhi * 8];
                const bf16x8 kf1 = *(const bf16x8*)&Ks[(keyloc + l15) * KS_STRIDE + 32 + lhi * 8];
                f32x4 a = (f32x4){0.f, 0.f, 0.f, 0.f};
                a = __builtin_amdgcn_mfma_f32_16x16x32_bf16(qf[0], kf0, a, 0, 0, 0);
                a = __builtin_amdgcn_mfma_f32_16x16x32_bf16(qf[1], kf1, a, 0, 0, 0);
                s[sg] = a;
            }
            float sv0[4], sv1[4], cmax[4];
            #pragma unroll
            for (int rg = 0; rg < 4; ++rg) {
                const int r = q0w + lhi * 4 + rg;
                const int key0 = kt * 64 + g * 32 + l15;
                const bool v0 = (key0 <= r) && (docs[g * 32 + l15] == myDoc[rg]);
                const bool v1 = (key0 + 16 <= r) && (docs[g * 32 + 16 + l15] == myDoc[rg]);
                sv0[rg] = v0 ? s[0][rg] : -INFINITY;
                sv1[rg] = v1 ? s[1][rg] : -INFINITY;
                cmax[rg] = fmaxf(sv0[rg], sv1[rg]);
            }
            #pragma unroll
            for (int off = 1; off < 16; off <<= 1)
                #pragma unroll
                for (int rg = 0; rg < 4; ++rg)
                    cmax[rg] = fmaxf(cmax[rg], __shfl_xor(cmax[rg], off, 64));
            float alpha[4], p0[4], p1[4], rsum[4];
            #pragma unroll
            for (int rg = 0; rg < 4; ++rg) {
                const float mn = fmaxf(mrow[rg], cmax[rg]);
                alpha[rg] = (mn == -INFINITY) ? 1.f : exp2f((mrow[rg] - mn) * LOG2E);
                p0[rg] = (sv0[rg] == -INFINITY) ? 0.f : exp2f((sv0[rg] - mn) * LOG2E);
                p1[rg] = (sv1[rg] == -INFINITY) ? 0.f : exp2f((sv1[rg] - mn) * LOG2E);
                rsum[rg] = p0[rg] + p1[rg];
                mrow[rg] = mn;
            }
            #pragma unroll
            for (int off = 1; off < 16; off <<= 1)
                #pragma unroll
                for (int rg = 0; rg < 4; ++rg)
                    rsum[rg] += __shfl_xor(rsum[rg], off, 64);
            #pragma unroll
            for (int rg = 0; rg < 4; ++rg)
                lrow[rg] = lrow[rg] * alpha[rg] + rsum[rg];
            #pragma unroll
            for (int nb = 0; nb < 4; ++nb)
                #pragma unroll
                for (int rg = 0; rg < 4; ++rg)
                    oacc[nb][rg] *= alpha[rg];
            float* pp = &Pw[wv][0];
            #pragma unroll
            for (int rg = 0; rg < 4; ++rg) {
                pp[(lhi * 4 + rg) * PW_STRIDE + l15] = p0[rg];
                pp[(lhi * 4 + rg) * PW_STRIDE + 16 + l15] = p1[rg];
            }
            const f32x4 pa = *(const f32x4*)&pp[l15 * PW_STRIDE + lhi * 8];
            const f32x4 pb = *(const f32x4*)&pp[l15 * PW_STRIDE + lhi * 8 + 4];
            bf16x8 pf;
            pf[0] = (__bf16)pa[0]; pf[1] = (__bf16)pa[1];
            pf[2] = (__bf16)pa[2]; pf[3] = (__bf16)pa[3];
            pf[4] = (__bf16)pb[0]; pf[5] = (__bf16)pb[1];
            pf[6] = (__bf16)pb[2]; pf[7] = (__bf16)pb[3];
            #pragma unroll
            for (int nb = 0; nb < 4; ++nb) {
                const bf16x8 vf = *(const bf16x8*)&Vt[(nb * 16 + l15) * VT_STRIDE + g * 32 + lhi * 8];
                oacc[nb] = __builtin_amdgcn_mfma_f32_16x16x32_bf16(pf, vf, oacc[nb], 0, 0, 0);
            }
        }
    }
    float inv[4];
    #pragma unroll
    for (int rg = 0; rg < 4; ++rg) inv[rg] = 1.f / lrow[rg];
    #pragma unroll
    for (int nb = 0; nb < 4; ++nb)
        #pragma unroll
        for (int rg = 0; rg < 4; ++rg)
            out[(size_t)(q0w + lhi * 4 + rg) * DIMM + h * 64 + nb * 16 + l15] =
                (__bf16)(oacc[nb][rg] * inv[rg]);
}

// ---------------------------------------------------------------------------
// SwiGLU on bf16 input: g[n][j] = silu(h[n][j]) * h[n][j+H], H=1<<shift
// ---------------------------------------------------------------------------
__global__ __launch_bounds__(256) void swiglu_bf2(
    const __bf16* __restrict__ h, __bf16* __restrict__ g, int shift)
{
    const int i4 = blockIdx.x * 256 + threadIdx.x;
    const int H = 1 << shift;
    const int n = (i4 * 4) >> shift;
    const int j = (i4 * 4) & (H - 1);
    const __bf16* hr = h + ((size_t)n << (shift + 1));
    BF4 a, b;
    a.u = *(const uint2*)(hr + j);
    b.u = *(const uint2*)(hr + H + j);
    BF4 o;
    #pragma unroll
    for (int u = 0; u < 4; ++u) {
        const float av = (float)a.h[u], bv = (float)b.h[u];
        o.h[u] = (__bf16)((av / (1.f + __expf(-av))) * bv);
    }
    *(uint2*)(g + (size_t)i4 * 4) = o.u;
}

// ---------------------------------------------------------------------------
// pmask on merged bf16 hh [N][8192] (cols 0..4095 = h1, 4096..8191 = h2):
// p[n][j] = silu(h1)*h2 * sc[n][j>>9]
// ---------------------------------------------------------------------------
__global__ __launch_bounds__(256) void pmask_bf2(
    const __bf16* __restrict__ hh, const float* __restrict__ sc,
    __bf16* __restrict__ p)
{
    const int i4 = blockIdx.x * 256 + threadIdx.x;
    const int n = i4 >> 10;
    const int j4 = i4 & 1023;
    const int e = j4 >> 7;
    const float s = sc[n * LE + e];
    const __bf16* hr = hh + (size_t)n * 8192 + j4 * 4;
    BF4 a, b;
    a.u = *(const uint2*)(hr);
    b.u = *(const uint2*)(hr + 4096);
    BF4 o;
    #pragma unroll
    for (int u = 0; u < 4; ++u) {
        const float av = (float)a.h[u], bv = (float)b.h[u];
        o.h[u] = (__bf16)((av / (1.f + __expf(-av))) * bv * s);
    }
    *(uint2*)(p + (size_t)i4 * 4) = o.u;
}

// ---------------------------------------------------------------------------
// Router: sc[n][e] dense (0 for unselected)
// ---------------------------------------------------------------------------
__global__ __launch_bounds__(64) void router_bf(
    const __bf16* __restrict__ xf, const float* __restrict__ tkeys,
    const float* __restrict__ rbias, const int* __restrict__ idx,
    const float* __restrict__ vals, float* __restrict__ sc)
{
    const int n = blockIdx.x;
    const int t = threadIdx.x;
    const int e0 = idx[n * 2 + 0], e1 = idx[n * 2 + 1];
    float a0 = 0.f, a1 = 0.f;
    for (int d = t; d < DIMM; d += 64) {
        const float xv = (float)xf[(size_t)n * DIMM + d];
        a0 += xv * tkeys[d * LE + e0];
        a1 += xv * tkeys[d * LE + e1];
    }
    #pragma unroll
    for (int off = 32; off > 0; off >>= 1) {
        a0 += __shfl_down(a0, off, 64);
        a1 += __shfl_down(a1, off, 64);
    }
    if (t == 0) {
        const float v0 = vals[n * 2 + 0] + a0 + rbias[e0];
        const float v1 = vals[n * 2 + 1] + a1 + rbias[e1];
        const float s0 = 1.f / (1.f + __expf(-v0));
        const float s1 = 1.f / (1.f + __expf(-v1));
        const float inv = 1.f / (s0 + s1);
        float r[LE];
        #pragma unroll
        for (int e = 0; e < LE; ++e) r[e] = 0.f;
        r[e0] += s0 * inv;
        r[e1] += s1 * inv;
        #pragma unroll
        for (int e = 0; e < LE; ++e) sc[n * LE + e] = r[e];
    }
}

// ---------------------------------------------------------------------------
// Host orchestration
// ---------------------------------------------------------------------------
struct Scratch {
    float *qkv, *xi, *t1, *sc, *xA, *xB;
    __bf16 *xn_bf, *attnO_bf, *xf_bf, *wbuf, *gact_bf, *gs_bf, *hh_bf, *hs_bf;
};

static void attn_block(const float* x_in, const __bf16* awT, const __bf16* aoT,
                       const float* ag, const int* doc, Scratch& w, hipStream_t s)
{
    rmsnorm_bf<<<NTOK, 256, 0, s>>>(x_in, ag, w.xn_bf);
    gemm_bf_t<float><<<dim3(24, 16), 256, 0, s>>>(w.xn_bf, awT, nullptr, w.qkv, NTOK, 3072, 1024);
    rotary_kernel<<<(NTOK * 512) / 256, 256, 0, s>>>(w.qkv);
    attn_mfma<<<dim3(HEADS, NTOK / 64), 256, 0, s>>>(w.qkv, doc, w.attnO_bf);
    gemm_bf_t<float><<<dim3(8, 16), 256, 0, s>>>(w.attnO_bf, aoT, x_in, w.xi, NTOK, 1024, 1024);
}

static void dense_layer_run(const float* x_in, float* x_out,
                            const float* aw, const float* ao,
                            const float* up, const float* down,
                            const float* ag, const float* fg,
                            const int* doc, Scratch& w, hipStream_t s)
{
    __bf16* awT = w.wbuf;
    __bf16* aoT = w.wbuf + 3145728;
    __bf16* upT = w.wbuf + 4194304;
    __bf16* dnT = w.wbuf + 12582912;
    transpose_cast<<<dim3(96, 32, 1), 256, 0, s>>>(aw, awT, 1024, 3072);
    transpose_cast<<<dim3(32, 32, 1), 256, 0, s>>>(ao, aoT, 1024, 1024);
    transpose_cast<<<dim3(256, 32, 1), 256, 0, s>>>(up, upT, 1024, 8192);
    transpose_cast<<<dim3(32, 128, 1), 256, 0, s>>>(down, dnT, 4096, 1024);
    attn_block(x_in, awT, aoT, ag, doc, w, s);
    rmsnorm_bf<<<NTOK, 256, 0, s>>>(w.xi, fg, w.xf_bf);
    gemm_bf_t<__bf16><<<dim3(64, 16), 256, 0, s>>>(w.xf_bf, upT, nullptr, w.hh_bf, NTOK, 8192, 1024);
    swiglu_bf2<<<(NTOK * FFN_H / 4) / 256, 256, 0, s>>>(w.hh_bf, w.gact_bf, 12);
    gemm_bf_t<float><<<dim3(8, 16), 256, 0, s>>>(w.gact_bf, dnT, w.xi, x_out, NTOK, 1024, 4096);
}

static void moe_layer_run(const float* x_in, float* x_out,
                          const float* aw, const float* ao,
                          const float* ag, const float* fg,
                          const float* experts, const float* tkeys,
                          const float* rbias, const float* sup,
                          const float* sdn, const int* idx, const float* vals,
                          const int* doc, Scratch& w, hipStream_t s)
{
    __bf16* awT  = w.wbuf;
    __bf16* aoT  = w.wbuf + 3145728;
    __bf16* w01T = w.wbuf + 4194304;   // w0T (4M) then w1T (4M), contiguous
    __bf16* w2c  = w.wbuf + 12582912;
    __bf16* supT = w.wbuf + 16777216;
    __bf16* sdnT = w.wbuf + 18874368;
    const size_t EW = (size_t)LE * DIMM * DIM_E;
    transpose_cast<<<dim3(96, 32, 1), 256, 0, s>>>(aw, awT, 1024, 3072);
    transpose_cast<<<dim3(32, 32, 1), 256, 0, s>>>(ao, aoT, 1024, 1024);
    transpose_cast<<<dim3(16, 32, 8), 256, 0, s>>>(experts, w01T, 1024, 512);
    transpose_cast<<<dim3(16, 32, 8), 256, 0, s>>>(experts + EW, w01T + 4194304, 1024, 512);
    cast_w2<<<16384, 256, 0, s>>>(experts + 2 * EW, w2c);
    transpose_cast<<<dim3(64, 32, 1), 256, 0, s>>>(sup, supT, 1024, 2048);
    transpose_cast<<<dim3(32, 32, 1), 256, 0, s>>>(sdn, sdnT, 1024, 1024);

    attn_block(x_in, awT, aoT, ag, doc, w, s);
    rmsnorm_bf<<<NTOK, 256, 0, s>>>(w.xi, fg, w.xf_bf);
    router_bf<<<NTOK, 64, 0, s>>>(w.xf_bf, tkeys, rbias, idx, vals, w.sc);
    // merged h1|h2 GEMM: N=8192 over contiguous w0T,w1T
    gemm_bf_t<__bf16><<<dim3(64, 16), 256, 0, s>>>(w.xf_bf, w01T, nullptr, w.hh_bf, NTOK, 8192, 1024);
    pmask_bf2<<<(NTOK * 4096 / 4) / 256, 256, 0, s>>>(w.hh_bf, w.sc, w.gact_bf);
    gemm_bf_t<__bf16><<<dim3(16, 16), 256, 0, s>>>(w.xf_bf, supT, nullptr, w.hs_bf, NTOK, 2048, 1024);
    swiglu_bf2<<<(NTOK * DIM_S / 4) / 256, 256, 0, s>>>(w.hs_bf, w.gs_bf, 10);
    gemm_bf_t<float><<<dim3(8, 16), 256, 0, s>>>(w.gs_bf, sdnT, w.xi, w.t1, NTOK, 1024, 1024);
    gemm_bf_t<float><<<dim3(8, 16), 256, 0, s>>>(w.gact_bf, w2c, w.t1, x_out, NTOK, 1024, 4096);
}

extern "C" void kernel_launch(void* const* d_in, const int* in_sizes, int n_in,
                              void* d_out, int out_size, void* d_ws, size_t ws_size,
                              hipStream_t stream)
{
    (void)in_sizes; (void)n_in; (void)out_size; (void)ws_size;
    const float* x       = (const float*)d_in[0];
    const int*   doc     = (const int*)d_in[1];
    const int*   indices = (const int*)d_in[2];
    const float* values  = (const float*)d_in[3];
    const float* d_aw    = (const float*)d_in[4];
    const float* d_ao    = (const float*)d_in[5];
    const float* d_up    = (const float*)d_in[6];
    const float* d_down  = (const float*)d_in[7];
    const float* d_ag    = (const float*)d_in[8];
    const float* d_fg    = (const float*)d_in[9];
    const float* m_aw    = (const float*)d_in[10];
    const float* m_ao    = (const float*)d_in[11];
    const float* m_ag    = (const float*)d_in[12];
    const float* m_fg    = (const float*)d_in[13];
    const float* m_ex    = (const float*)d_in[14];
    const float* m_tk    = (const float*)d_in[15];
    const float* m_rb    = (const float*)d_in[16];
    const float* m_sup   = (const float*)d_in[17];
    const float* m_sdn   = (const float*)d_in[18];

    Scratch w;
    float* f = (float*)d_ws;
    w.qkv = f; f += 6291456;     // 24 MB region (also gact_bf 16MB + gs_bf 4MB)
    w.xi  = f; f += 2097152;
    float* h12 = f; f += 16777216;   // 64 MB region: hh_bf (32MB) + hs_bf (8MB)
    w.t1  = h12 + 8388608;           // fp32 tmp in upper half of h12 region
    w.sc  = f; f += 16384;
    w.xA  = f; f += 2097152;
    w.xB  = f; f += 2097152;
    __bf16* b = (__bf16*)f;
    w.xn_bf    = b; b += 2097152;
    w.attnO_bf = b; b += 2097152;
    w.xf_bf    = b; b += 2097152;
    w.wbuf     = b; b += 19922944;
    w.gact_bf  = (__bf16*)w.qkv;
    w.gs_bf    = (__bf16*)w.qkv + 8388608;
    w.hh_bf    = (__bf16*)h12;                 // 2048*8192 bf16 = 32 MB
    w.hs_bf    = (__bf16*)w.t1 + 8388608;      // above t1's 2048*1024 fp32? no:
    // place hs_bf in the h12 region after hh_bf (byte offset 32MB);
    // t1 occupies byte offset 32MB..40MB (2048*1024 fp32 = 8MB) -> put hs after t1
    w.hs_bf    = (__bf16*)(h12 + 8388608 + 2097152);   // offset 40MB, 8MB used

    float* out = (float*)d_out;

    dense_layer_run(x, w.xA, d_aw, d_ao, d_up, d_down, d_ag, d_fg, doc, w, stream);
    const size_t EXL = (size_t)3 * LE * DIMM * DIM_E;
    moe_layer_run(w.xA, w.xB,
                  m_aw, m_ao, m_ag, m_fg,
                  m_ex, m_tk, m_rb, m_sup, m_sdn,
                  indices, values, doc, w, stream);
    moe_layer_run(w.xB, w.xA,
                  m_aw + (size_t)DIMM * 3 * DIMM, m_ao + (size_t)DIMM * DIMM,
                  m_ag + DIMM, m_fg + DIMM,
                  m_ex + EXL, m_tk + DIMM * LE, m_rb + LE,
                  m_sup + (size_t)DIMM * 2 * DIM_S, m_sdn + (size_t)DIM_S * DIMM,
                  indices + (size_t)NTOK * TOPK, values + (size_t)NTOK * TOPK,
                  doc, w, stream);
    dense_layer_run(w.xA, out,
                    d_aw + (size_t)DIMM * 3 * DIMM, d_ao + (size_t)DIMM * DIMM,
                    d_up + (size_t)DIMM * 2 * FFN_H, d_down + (size_t)FFN_H * DIMM,
                    d_ag + DIMM, d_fg + DIMM, doc, w, stream);
}